// Round 3
// baseline (864.259 us; speedup 1.0000x reference)
//
#include <hip/hip_runtime.h>
#include <math.h>

// Problem constants (from reference): B=8, H=W=32, D=512, NH=8, DKH=DVH=64
#define TOK 8192          // B*H*W tokens
#define DMODEL 512
#define SEQ 1024          // H*W keys per batch
#define NHEADS 8
#define DH 64
#define NBATCH 8

// ---------------------------------------------------------------------------
// GEMM: C[M,512] = (A[M,512] @ W[512,512] + bias[512]) * scale   (fp32)
// 64x64 tile per block, 256 threads, 4x4 microtile, K-tile 16.
// ---------------------------------------------------------------------------
__global__ __launch_bounds__(256) void gemm_bias(
    const float* __restrict__ A, const float* __restrict__ W,
    const float* __restrict__ bias, float* __restrict__ C, float scale) {
  __shared__ float As[16][65];   // [k][m] (transposed store), padded
  __shared__ float Bs[16][65];   // [k][n], padded
  const int t = threadIdx.x;
  const int tx = t & 15;        // micro col group
  const int ty = t >> 4;        // micro row group
  const int rowBase = blockIdx.y * 64;
  const int colBase = blockIdx.x * 64;

  float acc[4][4] = {};

  for (int k0 = 0; k0 < DMODEL; k0 += 16) {
    // Load A tile: 64 rows x 16 k, transposed into As[k][m]
    {
      const int r  = t >> 2;          // 0..63
      const int kq = (t & 3) * 4;     // 0,4,8,12
      const float4 a4 = *reinterpret_cast<const float4*>(
          &A[(size_t)(rowBase + r) * DMODEL + k0 + kq]);
      As[kq + 0][r] = a4.x; As[kq + 1][r] = a4.y;
      As[kq + 2][r] = a4.z; As[kq + 3][r] = a4.w;
    }
    // Load B tile: 16 k x 64 cols
    {
      const int kk = t >> 4;          // 0..15
      const int c  = (t & 15) * 4;
      const float4 b4 = *reinterpret_cast<const float4*>(
          &W[(size_t)(k0 + kk) * DMODEL + colBase + c]);
      Bs[kk][c + 0] = b4.x; Bs[kk][c + 1] = b4.y;
      Bs[kk][c + 2] = b4.z; Bs[kk][c + 3] = b4.w;
    }
    __syncthreads();
#pragma unroll
    for (int kk = 0; kk < 16; ++kk) {
      float a[4], b[4];
#pragma unroll
      for (int i = 0; i < 4; ++i) a[i] = As[kk][ty * 4 + i];
#pragma unroll
      for (int j = 0; j < 4; ++j) b[j] = Bs[kk][tx * 4 + j];
#pragma unroll
      for (int i = 0; i < 4; ++i)
#pragma unroll
        for (int j = 0; j < 4; ++j) acc[i][j] += a[i] * b[j];
    }
    __syncthreads();
  }

#pragma unroll
  for (int i = 0; i < 4; ++i) {
    const int row = rowBase + ty * 4 + i;
#pragma unroll
    for (int j = 0; j < 4; ++j) {
      const int col = colBase + tx * 4 + j;
      C[(size_t)row * DMODEL + col] = (acc[i][j] + bias[col]) * scale;
    }
  }
}

// ---------------------------------------------------------------------------
// Attention: per block = (b, head, 64-query tile). Flash-style over 16
// key tiles of 64. Scores in LDS; K and V share one LDS buffer (two phases).
// pos_logits is [B,1024,1024] effectively; mask is XOR(q_mask, k_mask)->-inf.
// Output layout: attn[token, h*64 + d]  (head-concatenated, ready for Wo).
// ---------------------------------------------------------------------------
__global__ __launch_bounds__(256) void attn_kernel(
    const float* __restrict__ qp, const float* __restrict__ kp,
    const float* __restrict__ vp, const float* __restrict__ pos,
    const int* __restrict__ qmask, const int* __restrict__ kmask,
    float* __restrict__ out) {
  const int qtile = blockIdx.x;  // 0..15
  const int h = blockIdx.y;      // 0..7
  const int b = blockIdx.z;      // 0..7
  const int t = threadIdx.x;
  const int qbase = qtile * 64;

  __shared__ float Qs[64][65];
  __shared__ float KV[64][65];   // K during phase1, V during phase2
  __shared__ float Ss[64][65];   // scores
  __shared__ int qm_s[64];
  __shared__ int km_s[64];

  // Load Q tile (64 rows x 64 dims) + q_mask
  {
    const int r = t >> 2;
    const int c0 = (t & 3) * 16;
    const float* src = &qp[((size_t)(b * SEQ + qbase + r)) * DMODEL + h * DH + c0];
#pragma unroll
    for (int cc = 0; cc < 16; cc += 4) {
      const float4 v = *reinterpret_cast<const float4*>(src + cc);
      Qs[r][c0 + cc + 0] = v.x; Qs[r][c0 + cc + 1] = v.y;
      Qs[r][c0 + cc + 2] = v.z; Qs[r][c0 + cc + 3] = v.w;
    }
    if (t < 64) qm_s[t] = qmask[b * SEQ + qbase + t];
  }

  // Running softmax state: thread (qr, seg) owns query qr, dims [seg*16, seg*16+16)
  const int qr = t & 63;
  const int seg = t >> 6;
  float m = -INFINITY;
  float l = 0.0f;
  float acc[16];
#pragma unroll
  for (int i = 0; i < 16; ++i) acc[i] = 0.0f;

  const size_t posBase = (size_t)b * SEQ * SEQ;

  for (int kt = 0; kt < 16; ++kt) {
    const int kbase = kt * 64;
    __syncthreads();  // previous phase2 done reading KV/Ss (also covers Q load)

    // Load K tile + k_mask
    {
      const int r = t >> 2;
      const int c0 = (t & 3) * 16;
      const float* src = &kp[((size_t)(b * SEQ + kbase + r)) * DMODEL + h * DH + c0];
#pragma unroll
      for (int cc = 0; cc < 16; cc += 4) {
        const float4 v = *reinterpret_cast<const float4*>(src + cc);
        KV[r][c0 + cc + 0] = v.x; KV[r][c0 + cc + 1] = v.y;
        KV[r][c0 + cc + 2] = v.z; KV[r][c0 + cc + 3] = v.w;
      }
      if (t < 64) km_s[t] = kmask[b * SEQ + kbase + t];
    }
    __syncthreads();

    // Phase 1: scores 64x64 = Q @ K^T (+pos, +mask). 16x16 thread grid, 4x4 micro.
    {
      const int tq = (t & 15) * 4;
      const int tk = (t >> 4) * 4;
      float sc[4][4] = {};
#pragma unroll 8
      for (int d = 0; d < DH; ++d) {
        float a[4], bb[4];
#pragma unroll
        for (int i = 0; i < 4; ++i) a[i] = Qs[tq + i][d];
#pragma unroll
        for (int j = 0; j < 4; ++j) bb[j] = KV[tk + j][d];
#pragma unroll
        for (int i = 0; i < 4; ++i)
#pragma unroll
          for (int j = 0; j < 4; ++j) sc[i][j] += a[i] * bb[j];
      }
#pragma unroll
      for (int i = 0; i < 4; ++i) {
        const int qg = qbase + tq + i;
        const bool qm = qm_s[tq + i] != 0;
#pragma unroll
        for (int j = 0; j < 4; ++j) {
          const int kg = kbase + tk + j;
          const bool xm = qm != (km_s[tk + j] != 0);
          const float s = sc[i][j] + pos[posBase + (size_t)qg * SEQ + kg];
          Ss[tq + i][tk + j] = xm ? -INFINITY : s;
        }
      }
    }
    __syncthreads();

    // Load V tile into KV (overwrites K)
    {
      const int r = t >> 2;
      const int c0 = (t & 3) * 16;
      const float* src = &vp[((size_t)(b * SEQ + kbase + r)) * DMODEL + h * DH + c0];
#pragma unroll
      for (int cc = 0; cc < 16; cc += 4) {
        const float4 v = *reinterpret_cast<const float4*>(src + cc);
        KV[r][c0 + cc + 0] = v.x; KV[r][c0 + cc + 1] = v.y;
        KV[r][c0 + cc + 2] = v.z; KV[r][c0 + cc + 3] = v.w;
      }
    }
    __syncthreads();

    // Phase 2: online softmax + P@V for this tile.
    {
      float tm = -INFINITY;
#pragma unroll 8
      for (int k = 0; k < 64; ++k) tm = fmaxf(tm, Ss[qr][k]);
      const float nm = fmaxf(m, tm);
      const float resc = (nm == -INFINITY) ? 1.0f : __expf(m - nm);
      l *= resc;
#pragma unroll
      for (int i = 0; i < 16; ++i) acc[i] *= resc;
      float psum = 0.0f;
      const int d0 = seg * 16;
#pragma unroll 4
      for (int k = 0; k < 64; ++k) {
        const float sv = Ss[qr][k];
        const float p = (sv == -INFINITY) ? 0.0f : __expf(sv - nm);
        psum += p;
#pragma unroll
        for (int dd = 0; dd < 16; ++dd) acc[dd] += p * KV[k][d0 + dd];
      }
      l += psum;
      m = nm;
    }
  }

  // Write out: attn[token, h*64 + seg*16 + dd] = acc/l
  {
    const float inv = 1.0f / l;
    float* dst = &out[((size_t)(b * SEQ + qbase + qr)) * DMODEL + h * DH + seg * 16];
#pragma unroll
    for (int dd = 0; dd < 16; ++dd) dst[dd] = acc[dd] * inv;
  }
}

// ---------------------------------------------------------------------------
extern "C" void kernel_launch(void* const* d_in, const int* in_sizes, int n_in,
                              void* d_out, int out_size, void* d_ws, size_t ws_size,
                              hipStream_t stream) {
  const float* q    = (const float*)d_in[0];
  const float* k    = (const float*)d_in[1];
  const int*   qm   = (const int*)d_in[2];
  const int*   km   = (const int*)d_in[3];
  const float* pos  = (const float*)d_in[4];
  const float* Wq   = (const float*)d_in[5];
  const float* bq   = (const float*)d_in[6];
  const float* Wk   = (const float*)d_in[7];
  const float* bk   = (const float*)d_in[8];
  const float* Wv   = (const float*)d_in[9];
  const float* bv   = (const float*)d_in[10];
  const float* Wo   = (const float*)d_in[11];
  const float* bo   = (const float*)d_in[12];
  float* out = (float*)d_out;

  float* qp   = (float*)d_ws;                    // [8192,512]
  float* kp   = qp + (size_t)TOK * DMODEL;       // [8192,512]
  float* vp   = kp + (size_t)TOK * DMODEL;       // [8192,512]
  float* attn = vp + (size_t)TOK * DMODEL;       // [8192,512]

  const dim3 gblock(256);
  const dim3 ggrid(DMODEL / 64, TOK / 64);       // (8, 128)

  // qp = (q @ Wq + bq) * dkh^-0.5
  hipLaunchKernelGGL(gemm_bias, ggrid, gblock, 0, stream, q, Wq, bq, qp, 0.125f);
  // kp = k @ Wk + bk
  hipLaunchKernelGGL(gemm_bias, ggrid, gblock, 0, stream, k, Wk, bk, kp, 1.0f);
  // vp = kp @ Wv + bv   (faithful quirk: V from projected K)
  hipLaunchKernelGGL(gemm_bias, ggrid, gblock, 0, stream, kp, Wv, bv, vp, 1.0f);

  // attention
  hipLaunchKernelGGL(attn_kernel, dim3(16, NHEADS, NBATCH), gblock, 0, stream,
                     qp, kp, vp, pos, qm, km, attn);

  // out = attn @ Wo + bo
  hipLaunchKernelGGL(gemm_bias, ggrid, gblock, 0, stream, attn, Wo, bo, out, 1.0f);
}

// Round 4
// 237.563 us; speedup vs baseline: 3.6380x; 3.6380x over previous
//
#include <hip/hip_runtime.h>
#include <math.h>

// Problem constants: B=8, H=W=32, D=512, NH=8, DKH=DVH=64
#define TOK 8192
#define DMODEL 512
#define SEQ 1024
#define NHEADS 8
#define DH 64
#define NBATCH 8

typedef __attribute__((ext_vector_type(8))) short short8v;   // 8 bf16 = 4 VGPR
typedef __attribute__((ext_vector_type(4))) float f32x4;

#define MFMA16(a, b, c) __builtin_amdgcn_mfma_f32_16x16x32_bf16(a, b, c, 0, 0, 0)

__device__ __forceinline__ unsigned short f2bf(float x) {
  union { float f; unsigned int u; } v; v.f = x;
  unsigned int r = v.u + 0x7fffu + ((v.u >> 16) & 1u);  // RNE
  return (unsigned short)(r >> 16);
}

// ---------------------------------------------------------------------------
// f32 -> bf16 elementwise (8 elems/thread)
// ---------------------------------------------------------------------------
__global__ __launch_bounds__(256) void cvt_kernel(const float* __restrict__ src,
                                                  unsigned short* __restrict__ dst,
                                                  int n8) {
  int i = blockIdx.x * 256 + threadIdx.x;
  if (i >= n8) return;
  const float4* s4 = reinterpret_cast<const float4*>(src);
  float4 a = s4[2 * (size_t)i], b = s4[2 * (size_t)i + 1];
  short8v o;
  o[0] = (short)f2bf(a.x); o[1] = (short)f2bf(a.y);
  o[2] = (short)f2bf(a.z); o[3] = (short)f2bf(a.w);
  o[4] = (short)f2bf(b.x); o[5] = (short)f2bf(b.y);
  o[6] = (short)f2bf(b.z); o[7] = (short)f2bf(b.w);
  *reinterpret_cast<short8v*>(dst + 8 * (size_t)i) = o;
}

// ---------------------------------------------------------------------------
// Weight transpose + convert: Wt[n][k] = bf16(W[k][n]), 512x512.
// grid (8 kt, 8 nt), 256 threads, 64x64 tiles via padded LDS.
// ---------------------------------------------------------------------------
__global__ __launch_bounds__(256) void wtr_kernel(const float* __restrict__ W,
                                                  unsigned short* __restrict__ Wt) {
  __shared__ unsigned short tile[64][72];
  const int kt = blockIdx.x, nt = blockIdx.y;
  const int t = threadIdx.x, r = t >> 2, c0 = (t & 3) * 16;
  const float* src = W + (size_t)(kt * 64 + r) * 512 + nt * 64 + c0;
  short8v v0, v1;
#pragma unroll
  for (int e = 0; e < 4; ++e) {
    float4 f = *reinterpret_cast<const float4*>(src + e * 4);
    short* dstv = (e < 2) ? (short*)&v0 : (short*)&v1;
    dstv[(e & 1) * 4 + 0] = (short)f2bf(f.x);
    dstv[(e & 1) * 4 + 1] = (short)f2bf(f.y);
    dstv[(e & 1) * 4 + 2] = (short)f2bf(f.z);
    dstv[(e & 1) * 4 + 3] = (short)f2bf(f.w);
  }
  *reinterpret_cast<short8v*>(&tile[r][c0]) = v0;
  *reinterpret_cast<short8v*>(&tile[r][c0 + 8]) = v1;
  __syncthreads();
  short8v o0, o1;
#pragma unroll
  for (int e = 0; e < 8; ++e) o0[e] = (short)tile[c0 + e][r];
#pragma unroll
  for (int e = 0; e < 8; ++e) o1[e] = (short)tile[c0 + 8 + e][r];
  unsigned short* dst = Wt + (size_t)(nt * 64 + r) * 512 + kt * 64 + c0;
  *reinterpret_cast<short8v*>(dst) = o0;
  *reinterpret_cast<short8v*>(dst + 8) = o1;
}

// ---------------------------------------------------------------------------
// V transpose: vt[(b*8+h)*64 + d][j] = vp[b*1024 + j][h*64 + d] (bf16 in/out)
// grid (16 jt, 8 h, 8 b)
// ---------------------------------------------------------------------------
__global__ __launch_bounds__(256) void vtr_kernel(const unsigned short* __restrict__ vp,
                                                  unsigned short* __restrict__ vt) {
  __shared__ unsigned short tile[64][72];
  const int jt = blockIdx.x, hh = blockIdx.y, bb = blockIdx.z;
  const int t = threadIdx.x, r = t >> 2, c0 = (t & 3) * 16;
  const unsigned short* src = vp + (size_t)(bb * SEQ + jt * 64 + r) * DMODEL + hh * DH + c0;
  *reinterpret_cast<short8v*>(&tile[r][c0]) = *reinterpret_cast<const short8v*>(src);
  *reinterpret_cast<short8v*>(&tile[r][c0 + 8]) = *reinterpret_cast<const short8v*>(src + 8);
  __syncthreads();
  short8v o0, o1;
#pragma unroll
  for (int e = 0; e < 8; ++e) o0[e] = (short)tile[c0 + e][r];
#pragma unroll
  for (int e = 0; e < 8; ++e) o1[e] = (short)tile[c0 + 8 + e][r];
  unsigned short* dst = vt + (size_t)((bb * 8 + hh) * 64 + r) * SEQ + jt * 64 + c0;
  *reinterpret_cast<short8v*>(dst) = o0;
  *reinterpret_cast<short8v*>(dst + 8) = o1;
}

// ---------------------------------------------------------------------------
// MFMA GEMM: C[M,512] = (A[M,512] @ Wt^T + bias) * scale
//   A bf16 row-major, Wt bf16 [n][k] (pre-transposed) -> symmetric X*Y^T form.
// Block: 128x64 tile, 256 thr (4 waves, 2x2), BK=64, padded LDS (stride 72).
// OUTF32: 0 -> bf16 out, 1 -> f32 out.
// ---------------------------------------------------------------------------
template <int OUTF32>
__global__ __launch_bounds__(256) void gemm_mfma(
    const unsigned short* __restrict__ A, const unsigned short* __restrict__ Wt,
    const float* __restrict__ bias, float scale, void* __restrict__ Cout) {
  __shared__ unsigned short Asl[128][72];
  __shared__ unsigned short Bsl[64][72];
  const int t = threadIdx.x;
  const int w = t >> 6, lane = t & 63, li = lane & 15, lg = lane >> 4;
  const int wr = w >> 1, wc = w & 1;
  const int rowBase = blockIdx.y * 128, colBase = blockIdx.x * 64;

  f32x4 zero4 = {0.f, 0.f, 0.f, 0.f};
  f32x4 acc[4][2];
#pragma unroll
  for (int mi = 0; mi < 4; ++mi)
#pragma unroll
    for (int nj = 0; nj < 2; ++nj) acc[mi][nj] = zero4;

  for (int k0 = 0; k0 < 512; k0 += 64) {
    {  // stage A: 128 rows x 64 k; thread: row t>>1, 32-ushort half t&1
      const int r = t >> 1, hf = (t & 1) * 32;
      const unsigned short* src = A + (size_t)(rowBase + r) * 512 + k0 + hf;
#pragma unroll
      for (int q = 0; q < 4; ++q)
        *reinterpret_cast<short8v*>(&Asl[r][hf + q * 8]) =
            *reinterpret_cast<const short8v*>(src + q * 8);
    }
    {  // stage Wt: 64 rows x 64 k; thread: row t>>2, 16-ushort quarter t&3
      const int r = t >> 2, q = (t & 3) * 16;
      const unsigned short* src = Wt + (size_t)(colBase + r) * 512 + k0 + q;
      *reinterpret_cast<short8v*>(&Bsl[r][q]) = *reinterpret_cast<const short8v*>(src);
      *reinterpret_cast<short8v*>(&Bsl[r][q + 8]) = *reinterpret_cast<const short8v*>(src + 8);
    }
    __syncthreads();
#pragma unroll
    for (int kk = 0; kk < 2; ++kk) {
      short8v af[4], bf[2];
#pragma unroll
      for (int mi = 0; mi < 4; ++mi)
        af[mi] = *reinterpret_cast<short8v*>(&Asl[wr * 64 + mi * 16 + li][kk * 32 + lg * 8]);
#pragma unroll
      for (int nj = 0; nj < 2; ++nj)
        bf[nj] = *reinterpret_cast<short8v*>(&Bsl[wc * 32 + nj * 16 + li][kk * 32 + lg * 8]);
#pragma unroll
      for (int mi = 0; mi < 4; ++mi)
#pragma unroll
        for (int nj = 0; nj < 2; ++nj) acc[mi][nj] = MFMA16(af[mi], bf[nj], acc[mi][nj]);
    }
    __syncthreads();
  }
  // epilogue: D row = lg*4+r, col = li within each 16x16 tile
#pragma unroll
  for (int nj = 0; nj < 2; ++nj) {
    const int col = colBase + wc * 32 + nj * 16 + li;
    const float bv = bias[col];
#pragma unroll
    for (int mi = 0; mi < 4; ++mi) {
#pragma unroll
      for (int r = 0; r < 4; ++r) {
        const int row = rowBase + wr * 64 + mi * 16 + lg * 4 + r;
        const float v = (acc[mi][nj][r] + bv) * scale;
        if (OUTF32)
          reinterpret_cast<float*>(Cout)[(size_t)row * 512 + col] = v;
        else
          reinterpret_cast<unsigned short*>(Cout)[(size_t)row * 512 + col] = f2bf(v);
      }
    }
  }
}

// ---------------------------------------------------------------------------
// MFMA flash attention. Block = (b, h, 64-query tile); 4 waves x 16-q strips.
// Q,K frags direct from global bf16; S via LDS; wave-parallel online softmax
// (4 lanes/row); P bf16 in padded LDS; PV from pre-transposed global vt.
// ---------------------------------------------------------------------------
__global__ __launch_bounds__(256) void attn_mfma(
    const unsigned short* __restrict__ qp, const unsigned short* __restrict__ kp,
    const unsigned short* __restrict__ vt, const float* __restrict__ pos,
    const int* __restrict__ qmask, const int* __restrict__ kmask,
    unsigned short* __restrict__ outb) {
  // wgid = qtile + 16*b + 128*h: same (b,qtile) across heads -> same XCD slot
  const int wg = blockIdx.x;
  const int h = wg >> 7, b = (wg >> 4) & 7, qtile = wg & 15;
  const int qbase = qtile * 64;
  const int t = threadIdx.x, w = t >> 6, lane = t & 63, li = lane & 15, lg = lane >> 4;
  const int wq = w * 16;

  __shared__ float S_lds[64][65];
  __shared__ unsigned short P_lds[64][72];
  __shared__ float m_row[64], l_row[64], r_row[64];
  __shared__ int qm_s[64], km_s[64];

  if (t < 64) {
    m_row[t] = -3e38f;
    l_row[t] = 0.f;
    qm_s[t] = qmask[b * SEQ + qbase + t];
  }

  const size_t qrow = (size_t)(b * SEQ + qbase + wq + li) * DMODEL + h * DH;
  const short8v qf0 = *reinterpret_cast<const short8v*>(qp + qrow + lg * 8);
  const short8v qf1 = *reinterpret_cast<const short8v*>(qp + qrow + 32 + lg * 8);

  f32x4 zero4 = {0.f, 0.f, 0.f, 0.f};
  f32x4 acc_o[4];
#pragma unroll
  for (int n = 0; n < 4; ++n) acc_o[n] = zero4;

  const int sr = t >> 2, sg = t & 3, sc0 = (t & 3) * 16;  // softmax row/segment

  for (int kt = 0; kt < 16; ++kt) {
    const int kbase = kt * 64;
    if (t < 64) km_s[t] = kmask[b * SEQ + kbase + t];

    // ---- QK^T: wave w computes S[wq..wq+15][0..63] of this tile
    const unsigned short* kpb = kp + (size_t)(b * SEQ + kbase) * DMODEL + h * DH;
#pragma unroll
    for (int n = 0; n < 4; ++n) {
      const unsigned short* kr = kpb + (size_t)(n * 16 + li) * DMODEL;
      short8v kf0 = *reinterpret_cast<const short8v*>(kr + lg * 8);
      short8v kf1 = *reinterpret_cast<const short8v*>(kr + 32 + lg * 8);
      f32x4 s = zero4;
      s = MFMA16(qf0, kf0, s);
      s = MFMA16(qf1, kf1, s);
#pragma unroll
      for (int r = 0; r < 4; ++r) S_lds[wq + lg * 4 + r][n * 16 + li] = s[r];
    }
    __syncthreads();

    // ---- online softmax: thread t owns row sr, cols sc0..sc0+15
    {
      const int qmr = qm_s[sr];
      const float* pp = pos + ((size_t)b * SEQ + qbase + sr) * SEQ + kbase + sc0;
      float sv[16];
      float tmax = -3e38f;
#pragma unroll
      for (int e = 0; e < 16; ++e) {
        float x = S_lds[sr][sc0 + e] + pp[e];
        if ((qmr != 0) != (km_s[sc0 + e] != 0)) x = -1e30f;
        sv[e] = x;
        tmax = fmaxf(tmax, x);
      }
      tmax = fmaxf(tmax, __shfl_xor(tmax, 1));
      tmax = fmaxf(tmax, __shfl_xor(tmax, 2));
      const float mo = m_row[sr];
      const float mn = fmaxf(mo, tmax);
      const float rs = __expf(mo - mn);
      float psum = 0.f;
      unsigned int pk[8];
#pragma unroll
      for (int e2 = 0; e2 < 8; ++e2) {
        float p0 = __expf(sv[2 * e2] - mn);
        float p1 = __expf(sv[2 * e2 + 1] - mn);
        psum += p0 + p1;
        pk[e2] = (unsigned int)f2bf(p0) | ((unsigned int)f2bf(p1) << 16);
      }
      psum += __shfl_xor(psum, 1);
      psum += __shfl_xor(psum, 2);
      if (sg == 0) {
        m_row[sr] = mn;
        l_row[sr] = l_row[sr] * rs + psum;
        r_row[sr] = rs;
      }
#pragma unroll
      for (int e2 = 0; e2 < 8; ++e2)
        *reinterpret_cast<unsigned int*>(&P_lds[sr][sc0 + 2 * e2]) = pk[e2];
    }
    __syncthreads();

    // ---- rescale + PV
    {
      float rs[4];
#pragma unroll
      for (int r = 0; r < 4; ++r) rs[r] = r_row[wq + lg * 4 + r];
#pragma unroll
      for (int n = 0; n < 4; ++n)
#pragma unroll
        for (int r = 0; r < 4; ++r) acc_o[n][r] *= rs[r];

      short8v pf0 = *reinterpret_cast<short8v*>(&P_lds[wq + li][lg * 8]);
      short8v pf1 = *reinterpret_cast<short8v*>(&P_lds[wq + li][32 + lg * 8]);
      const unsigned short* vtb = vt + (size_t)((b * 8 + h) * 64) * SEQ + kbase;
#pragma unroll
      for (int n = 0; n < 4; ++n) {
        const unsigned short* vr = vtb + (size_t)(n * 16 + li) * SEQ;
        short8v vf0 = *reinterpret_cast<const short8v*>(vr + lg * 8);
        short8v vf1 = *reinterpret_cast<const short8v*>(vr + 32 + lg * 8);
        acc_o[n] = MFMA16(pf0, vf0, acc_o[n]);
        acc_o[n] = MFMA16(pf1, vf1, acc_o[n]);
      }
    }
  }

  // ---- epilogue: divide by l, write bf16 head-concatenated
  float inv[4];
#pragma unroll
  for (int r = 0; r < 4; ++r) inv[r] = 1.f / l_row[wq + lg * 4 + r];
  unsigned short* ob = outb + (size_t)(b * SEQ + qbase + wq) * DMODEL + h * DH;
#pragma unroll
  for (int n = 0; n < 4; ++n)
#pragma unroll
    for (int r = 0; r < 4; ++r)
      ob[(size_t)(lg * 4 + r) * DMODEL + n * 16 + li] = f2bf(acc_o[n][r] * inv[r]);
}

// ---------------------------------------------------------------------------
extern "C" void kernel_launch(void* const* d_in, const int* in_sizes, int n_in,
                              void* d_out, int out_size, void* d_ws, size_t ws_size,
                              hipStream_t stream) {
  const float* q   = (const float*)d_in[0];
  const float* k   = (const float*)d_in[1];
  const int*   qm  = (const int*)d_in[2];
  const int*   km  = (const int*)d_in[3];
  const float* pos = (const float*)d_in[4];
  const float* Wq  = (const float*)d_in[5];
  const float* bq  = (const float*)d_in[6];
  const float* Wk  = (const float*)d_in[7];
  const float* bk  = (const float*)d_in[8];
  const float* Wv  = (const float*)d_in[9];
  const float* bv  = (const float*)d_in[10];
  const float* Wo  = (const float*)d_in[11];
  const float* bo  = (const float*)d_in[12];
  float* out = (float*)d_out;

  char* ws = (char*)d_ws;
  const size_t MB8 = (size_t)TOK * DMODEL * 2;  // 8 MB per bf16 [8192][512]
  unsigned short* qb    = (unsigned short*)(ws);
  unsigned short* kb    = (unsigned short*)(ws + MB8);
  unsigned short* qpb   = (unsigned short*)(ws + 2 * MB8);
  unsigned short* kpb   = (unsigned short*)(ws + 3 * MB8);
  unsigned short* vpb   = (unsigned short*)(ws + 4 * MB8);
  unsigned short* attnb = (unsigned short*)(ws + 5 * MB8);
  unsigned short* vtb   = (unsigned short*)(ws + 6 * MB8);
  unsigned short* Wqt   = (unsigned short*)(ws + 7 * MB8);
  unsigned short* Wkt   = Wqt + (size_t)512 * 512;
  unsigned short* Wvt   = Wkt + (size_t)512 * 512;
  unsigned short* Wot   = Wvt + (size_t)512 * 512;

  const int n8 = TOK * DMODEL / 8;  // 524288
  hipLaunchKernelGGL(cvt_kernel, dim3(n8 / 256), dim3(256), 0, stream, q, qb, n8);
  hipLaunchKernelGGL(cvt_kernel, dim3(n8 / 256), dim3(256), 0, stream, k, kb, n8);
  hipLaunchKernelGGL(wtr_kernel, dim3(8, 8), dim3(256), 0, stream, Wq, Wqt);
  hipLaunchKernelGGL(wtr_kernel, dim3(8, 8), dim3(256), 0, stream, Wk, Wkt);
  hipLaunchKernelGGL(wtr_kernel, dim3(8, 8), dim3(256), 0, stream, Wv, Wvt);
  hipLaunchKernelGGL(wtr_kernel, dim3(8, 8), dim3(256), 0, stream, Wo, Wot);

  const dim3 ggrid(DMODEL / 64, TOK / 128);  // (8, 64)
  hipLaunchKernelGGL((gemm_mfma<0>), ggrid, dim3(256), 0, stream, qb, Wqt, bq, 0.125f, qpb);
  hipLaunchKernelGGL((gemm_mfma<0>), ggrid, dim3(256), 0, stream, kb, Wkt, bk, 1.0f, kpb);
  hipLaunchKernelGGL((gemm_mfma<0>), ggrid, dim3(256), 0, stream, kpb, Wvt, bv, 1.0f, vpb);

  hipLaunchKernelGGL(vtr_kernel, dim3(16, 8, 8), dim3(256), 0, stream, vpb, vtb);

  hipLaunchKernelGGL(attn_mfma, dim3(NHEADS * 16 * NBATCH), dim3(256), 0, stream,
                     qpb, kpb, vtb, pos, qm, km, attnb);

  hipLaunchKernelGGL((gemm_mfma<1>), ggrid, dim3(256), 0, stream, attnb, Wot, bo, 1.0f, out);
}

// Round 5
// 233.560 us; speedup vs baseline: 3.7004x; 1.0171x over previous
//
#include <hip/hip_runtime.h>
#include <math.h>

// Problem constants: B=8, H=W=32, D=512, NH=8, DKH=DVH=64
#define TOK 8192
#define DMODEL 512
#define SEQ 1024
#define NHEADS 8
#define DH 64
#define NBATCH 8

typedef __attribute__((ext_vector_type(8))) short short8v;   // 8 bf16 = 4 VGPR
typedef __attribute__((ext_vector_type(4))) float f32x4;

#define MFMA16(a, b, c) __builtin_amdgcn_mfma_f32_16x16x32_bf16(a, b, c, 0, 0, 0)

__device__ __forceinline__ unsigned short f2bf(float x) {
  union { float f; unsigned int u; } v; v.f = x;
  unsigned int r = v.u + 0x7fffu + ((v.u >> 16) & 1u);  // RNE
  return (unsigned short)(r >> 16);
}

// ---------------------------------------------------------------------------
// f32 -> bf16 elementwise (8 elems/thread)
// ---------------------------------------------------------------------------
__global__ __launch_bounds__(256) void cvt_kernel(const float* __restrict__ src,
                                                  unsigned short* __restrict__ dst,
                                                  int n8) {
  int i = blockIdx.x * 256 + threadIdx.x;
  if (i >= n8) return;
  const float4* s4 = reinterpret_cast<const float4*>(src);
  float4 a = s4[2 * (size_t)i], b = s4[2 * (size_t)i + 1];
  short8v o;
  o[0] = (short)f2bf(a.x); o[1] = (short)f2bf(a.y);
  o[2] = (short)f2bf(a.z); o[3] = (short)f2bf(a.w);
  o[4] = (short)f2bf(b.x); o[5] = (short)f2bf(b.y);
  o[6] = (short)f2bf(b.z); o[7] = (short)f2bf(b.w);
  *reinterpret_cast<short8v*>(dst + 8 * (size_t)i) = o;
}

// ---------------------------------------------------------------------------
// Weight transpose + convert: Wt[n][k] = bf16(W[k][n]), 512x512.
// ---------------------------------------------------------------------------
__global__ __launch_bounds__(256) void wtr_kernel(const float* __restrict__ W,
                                                  unsigned short* __restrict__ Wt) {
  __shared__ unsigned short tile[64][72];
  const int kt = blockIdx.x, nt = blockIdx.y;
  const int t = threadIdx.x, r = t >> 2, c0 = (t & 3) * 16;
  const float* src = W + (size_t)(kt * 64 + r) * 512 + nt * 64 + c0;
  short8v v0, v1;
#pragma unroll
  for (int e = 0; e < 4; ++e) {
    float4 f = *reinterpret_cast<const float4*>(src + e * 4);
    short* dstv = (e < 2) ? (short*)&v0 : (short*)&v1;
    dstv[(e & 1) * 4 + 0] = (short)f2bf(f.x);
    dstv[(e & 1) * 4 + 1] = (short)f2bf(f.y);
    dstv[(e & 1) * 4 + 2] = (short)f2bf(f.z);
    dstv[(e & 1) * 4 + 3] = (short)f2bf(f.w);
  }
  *reinterpret_cast<short8v*>(&tile[r][c0]) = v0;
  *reinterpret_cast<short8v*>(&tile[r][c0 + 8]) = v1;
  __syncthreads();
  short8v o0, o1;
#pragma unroll
  for (int e = 0; e < 8; ++e) o0[e] = (short)tile[c0 + e][r];
#pragma unroll
  for (int e = 0; e < 8; ++e) o1[e] = (short)tile[c0 + 8 + e][r];
  unsigned short* dst = Wt + (size_t)(nt * 64 + r) * 512 + kt * 64 + c0;
  *reinterpret_cast<short8v*>(dst) = o0;
  *reinterpret_cast<short8v*>(dst + 8) = o1;
}

// ---------------------------------------------------------------------------
// V transpose: vt[(b*8+h)*64 + d][j] = vp[b*1024 + j][h*64 + d] (bf16 in/out)
// ---------------------------------------------------------------------------
__global__ __launch_bounds__(256) void vtr_kernel(const unsigned short* __restrict__ vp,
                                                  unsigned short* __restrict__ vt) {
  __shared__ unsigned short tile[64][72];
  const int jt = blockIdx.x, hh = blockIdx.y, bb = blockIdx.z;
  const int t = threadIdx.x, r = t >> 2, c0 = (t & 3) * 16;
  const unsigned short* src = vp + (size_t)(bb * SEQ + jt * 64 + r) * DMODEL + hh * DH + c0;
  *reinterpret_cast<short8v*>(&tile[r][c0]) = *reinterpret_cast<const short8v*>(src);
  *reinterpret_cast<short8v*>(&tile[r][c0 + 8]) = *reinterpret_cast<const short8v*>(src + 8);
  __syncthreads();
  short8v o0, o1;
#pragma unroll
  for (int e = 0; e < 8; ++e) o0[e] = (short)tile[c0 + e][r];
#pragma unroll
  for (int e = 0; e < 8; ++e) o1[e] = (short)tile[c0 + 8 + e][r];
  unsigned short* dst = vt + (size_t)((bb * 8 + hh) * 64 + r) * SEQ + jt * 64 + c0;
  *reinterpret_cast<short8v*>(dst) = o0;
  *reinterpret_cast<short8v*>(dst + 8) = o1;
}

// ---------------------------------------------------------------------------
// MFMA GEMM: C[M,512] = (A[M,512] @ Wt^T + bias) * scale  (unchanged from R4)
// ---------------------------------------------------------------------------
template <int OUTF32>
__global__ __launch_bounds__(256) void gemm_mfma(
    const unsigned short* __restrict__ A, const unsigned short* __restrict__ Wt,
    const float* __restrict__ bias, float scale, void* __restrict__ Cout) {
  __shared__ unsigned short Asl[128][72];
  __shared__ unsigned short Bsl[64][72];
  const int t = threadIdx.x;
  const int w = t >> 6, lane = t & 63, li = lane & 15, lg = lane >> 4;
  const int wr = w >> 1, wc = w & 1;
  const int rowBase = blockIdx.y * 128, colBase = blockIdx.x * 64;

  f32x4 zero4 = {0.f, 0.f, 0.f, 0.f};
  f32x4 acc[4][2];
#pragma unroll
  for (int mi = 0; mi < 4; ++mi)
#pragma unroll
    for (int nj = 0; nj < 2; ++nj) acc[mi][nj] = zero4;

  for (int k0 = 0; k0 < 512; k0 += 64) {
    {
      const int r = t >> 1, hf = (t & 1) * 32;
      const unsigned short* src = A + (size_t)(rowBase + r) * 512 + k0 + hf;
#pragma unroll
      for (int q = 0; q < 4; ++q)
        *reinterpret_cast<short8v*>(&Asl[r][hf + q * 8]) =
            *reinterpret_cast<const short8v*>(src + q * 8);
    }
    {
      const int r = t >> 2, q = (t & 3) * 16;
      const unsigned short* src = Wt + (size_t)(colBase + r) * 512 + k0 + q;
      *reinterpret_cast<short8v*>(&Bsl[r][q]) = *reinterpret_cast<const short8v*>(src);
      *reinterpret_cast<short8v*>(&Bsl[r][q + 8]) = *reinterpret_cast<const short8v*>(src + 8);
    }
    __syncthreads();
#pragma unroll
    for (int kk = 0; kk < 2; ++kk) {
      short8v af[4], bf[2];
#pragma unroll
      for (int mi = 0; mi < 4; ++mi)
        af[mi] = *reinterpret_cast<short8v*>(&Asl[wr * 64 + mi * 16 + li][kk * 32 + lg * 8]);
#pragma unroll
      for (int nj = 0; nj < 2; ++nj)
        bf[nj] = *reinterpret_cast<short8v*>(&Bsl[wc * 32 + nj * 16 + li][kk * 32 + lg * 8]);
#pragma unroll
      for (int mi = 0; mi < 4; ++mi)
#pragma unroll
        for (int nj = 0; nj < 2; ++nj) acc[mi][nj] = MFMA16(af[mi], bf[nj], acc[mi][nj]);
    }
    __syncthreads();
  }
#pragma unroll
  for (int nj = 0; nj < 2; ++nj) {
    const int col = colBase + wc * 32 + nj * 16 + li;
    const float bv = bias[col];
#pragma unroll
    for (int mi = 0; mi < 4; ++mi) {
#pragma unroll
      for (int r = 0; r < 4; ++r) {
        const int row = rowBase + wr * 64 + mi * 16 + lg * 4 + r;
        const float v = (acc[mi][nj][r] + bv) * scale;
        if (OUTF32)
          reinterpret_cast<float*>(Cout)[(size_t)row * 512 + col] = v;
        else
          reinterpret_cast<unsigned short*>(Cout)[(size_t)row * 512 + col] = f2bf(v);
      }
    }
  }
}

// ---------------------------------------------------------------------------
// Barrier-free MFMA flash attention.
// Block = (b, h, 64-q tile), 4 waves x 16-q strips; each wave fully
// independent: softmax done in-register in MFMA D-layout (row spread over the
// 16 `li` lanes -> shfl_xor(1,2,4,8) row reductions). P transposed to A-frag
// layout via a PER-WAVE LDS region (no __syncthreads anywhere).
// D-layout (verified R4): col = lane&15, row = (lane>>4)*4 + reg.
// ---------------------------------------------------------------------------
__global__ __launch_bounds__(256) void attn_mfma(
    const unsigned short* __restrict__ qp, const unsigned short* __restrict__ kp,
    const unsigned short* __restrict__ vt, const float* __restrict__ pos,
    const int* __restrict__ qmask, const int* __restrict__ kmask,
    unsigned short* __restrict__ outb) {
  const int wg = blockIdx.x;           // qtile + 16*b + 128*h (h-stride ≡ 0 mod 8 XCDs)
  const int h = wg >> 7, b = (wg >> 4) & 7, qtile = wg & 15;
  const int qbase = qtile * 64;
  const int t = threadIdx.x, w = t >> 6, lane = t & 63, li = lane & 15, lg = lane >> 4;
  const int wq = w * 16;

  __shared__ unsigned short P_lds[2][64][72];  // double-buffered, per-wave rows

  // Q fragments (A-operand): row wq+li, k-chunks lg*8
  const size_t qrow = (size_t)(b * SEQ + qbase + wq + li) * DMODEL + h * DH;
  const short8v qf0 = *reinterpret_cast<const short8v*>(qp + qrow + lg * 8);
  const short8v qf1 = *reinterpret_cast<const short8v*>(qp + qrow + 32 + lg * 8);

  // q_mask for my 4 rows (fixed across k-tiles)
  int qmr[4];
#pragma unroll
  for (int r = 0; r < 4; ++r)
    qmr[r] = qmask[b * SEQ + qbase + wq + lg * 4 + r];

  f32x4 zero4 = {0.f, 0.f, 0.f, 0.f};
  f32x4 acc_o[4];
#pragma unroll
  for (int n = 0; n < 4; ++n) acc_o[n] = zero4;
  float m[4], l[4];
#pragma unroll
  for (int r = 0; r < 4; ++r) { m[r] = -3e38f; l[r] = 0.f; }

  // hoisted per-lane address bases
  const float* posrow = pos + ((size_t)b * SEQ + qbase + wq + lg * 4) * SEQ + li;
  const int* kmb = kmask + b * SEQ + li;
  const unsigned short* kpl = kp + (size_t)(b * SEQ + li) * DMODEL + h * DH + lg * 8;
  const unsigned short* vtl = vt + (size_t)((b * 8 + h) * 64 + li) * SEQ + lg * 8;

  for (int kt = 0; kt < 16; ++kt) {
    const int kbase = kt * 64;

    // issue mask + pos loads early (consumed after QK^T)
    int kmv[4];
#pragma unroll
    for (int n = 0; n < 4; ++n) kmv[n] = kmb[kbase + n * 16];
    float pv[4][4];  // [r][n]
#pragma unroll
    for (int r = 0; r < 4; ++r)
#pragma unroll
      for (int n = 0; n < 4; ++n) pv[r][n] = posrow[(size_t)r * SEQ + kbase + n * 16];

    // ---- QK^T: s[n] = S[rows wq+lg*4+..][cols n*16+li]
    f32x4 s[4];
    __builtin_amdgcn_s_setprio(1);
#pragma unroll
    for (int n = 0; n < 4; ++n) {
      const unsigned short* kr = kpl + (size_t)(kbase + n * 16) * DMODEL;
      short8v kf0 = *reinterpret_cast<const short8v*>(kr);
      short8v kf1 = *reinterpret_cast<const short8v*>(kr + 32);
      s[n] = MFMA16(qf0, kf0, zero4);
      s[n] = MFMA16(qf1, kf1, s[n]);
    }
    __builtin_amdgcn_s_setprio(0);

    // ---- in-register online softmax (row over 16 li lanes)
    float x[4][4];  // [n][r]
    float tmax[4];
#pragma unroll
    for (int r = 0; r < 4; ++r) tmax[r] = -3e38f;
#pragma unroll
    for (int n = 0; n < 4; ++n)
#pragma unroll
      for (int r = 0; r < 4; ++r) {
        float xx = s[n][r] + pv[r][n];
        if ((qmr[r] != 0) != (kmv[n] != 0)) xx = -1e30f;
        x[n][r] = xx;
        tmax[r] = fmaxf(tmax[r], xx);
      }
#pragma unroll
    for (int r = 0; r < 4; ++r) {
      tmax[r] = fmaxf(tmax[r], __shfl_xor(tmax[r], 1));
      tmax[r] = fmaxf(tmax[r], __shfl_xor(tmax[r], 2));
      tmax[r] = fmaxf(tmax[r], __shfl_xor(tmax[r], 4));
      tmax[r] = fmaxf(tmax[r], __shfl_xor(tmax[r], 8));
    }
    float rs[4], ps[4];
#pragma unroll
    for (int r = 0; r < 4; ++r) {
      const float mn = fmaxf(m[r], tmax[r]);
      rs[r] = __expf(m[r] - mn);
      m[r] = mn;
      ps[r] = 0.f;
    }
#pragma unroll
    for (int n = 0; n < 4; ++n)
#pragma unroll
      for (int r = 0; r < 4; ++r) {
        const float p = __expf(x[n][r] - m[r]);
        x[n][r] = p;
        ps[r] += p;
      }
#pragma unroll
    for (int r = 0; r < 4; ++r) {
      ps[r] += __shfl_xor(ps[r], 1);
      ps[r] += __shfl_xor(ps[r], 2);
      ps[r] += __shfl_xor(ps[r], 4);
      ps[r] += __shfl_xor(ps[r], 8);
      l[r] = l[r] * rs[r] + ps[r];
    }
#pragma unroll
    for (int n = 0; n < 4; ++n)
#pragma unroll
      for (int r = 0; r < 4; ++r) acc_o[n][r] *= rs[r];

    // ---- P (D-layout) -> LDS -> A-frag layout. Per-wave region, no barrier.
    unsigned short (*P)[72] = P_lds[kt & 1];
#pragma unroll
    for (int n = 0; n < 4; ++n)
#pragma unroll
      for (int r = 0; r < 4; ++r)
        P[wq + lg * 4 + r][n * 16 + li] = f2bf(x[n][r]);
    asm volatile("s_waitcnt lgkmcnt(0)" ::: "memory");
    __builtin_amdgcn_sched_barrier(0);
    const short8v pf0 = *reinterpret_cast<short8v*>(&P[wq + li][lg * 8]);
    const short8v pf1 = *reinterpret_cast<short8v*>(&P[wq + li][32 + lg * 8]);

    // ---- PV from pre-transposed vt
    __builtin_amdgcn_s_setprio(1);
#pragma unroll
    for (int n = 0; n < 4; ++n) {
      const unsigned short* vr = vtl + (size_t)(n * 16) * SEQ + kbase;
      short8v vf0 = *reinterpret_cast<const short8v*>(vr);
      short8v vf1 = *reinterpret_cast<const short8v*>(vr + 32);
      acc_o[n] = MFMA16(pf0, vf0, acc_o[n]);
      acc_o[n] = MFMA16(pf1, vf1, acc_o[n]);
    }
    __builtin_amdgcn_s_setprio(0);
  }

  // ---- epilogue
  float inv[4];
#pragma unroll
  for (int r = 0; r < 4; ++r) inv[r] = 1.f / l[r];
  unsigned short* ob = outb + (size_t)(b * SEQ + qbase + wq) * DMODEL + h * DH;
#pragma unroll
  for (int n = 0; n < 4; ++n)
#pragma unroll
    for (int r = 0; r < 4; ++r)
      ob[(size_t)(lg * 4 + r) * DMODEL + n * 16 + li] = f2bf(acc_o[n][r] * inv[r]);
}

// ---------------------------------------------------------------------------
extern "C" void kernel_launch(void* const* d_in, const int* in_sizes, int n_in,
                              void* d_out, int out_size, void* d_ws, size_t ws_size,
                              hipStream_t stream) {
  const float* q   = (const float*)d_in[0];
  const float* k   = (const float*)d_in[1];
  const int*   qm  = (const int*)d_in[2];
  const int*   km  = (const int*)d_in[3];
  const float* pos = (const float*)d_in[4];
  const float* Wq  = (const float*)d_in[5];
  const float* bq  = (const float*)d_in[6];
  const float* Wk  = (const float*)d_in[7];
  const float* bk  = (const float*)d_in[8];
  const float* Wv  = (const float*)d_in[9];
  const float* bv  = (const float*)d_in[10];
  const float* Wo  = (const float*)d_in[11];
  const float* bo  = (const float*)d_in[12];
  float* out = (float*)d_out;

  char* ws = (char*)d_ws;
  const size_t MB8 = (size_t)TOK * DMODEL * 2;  // 8 MB per bf16 [8192][512]
  unsigned short* qb    = (unsigned short*)(ws);
  unsigned short* kb    = (unsigned short*)(ws + MB8);
  unsigned short* qpb   = (unsigned short*)(ws + 2 * MB8);
  unsigned short* kpb   = (unsigned short*)(ws + 3 * MB8);
  unsigned short* vpb   = (unsigned short*)(ws + 4 * MB8);
  unsigned short* attnb = (unsigned short*)(ws + 5 * MB8);
  unsigned short* vtb   = (unsigned short*)(ws + 6 * MB8);
  unsigned short* Wqt   = (unsigned short*)(ws + 7 * MB8);
  unsigned short* Wkt   = Wqt + (size_t)512 * 512;
  unsigned short* Wvt   = Wkt + (size_t)512 * 512;
  unsigned short* Wot   = Wvt + (size_t)512 * 512;

  const int n8 = TOK * DMODEL / 8;
  hipLaunchKernelGGL(cvt_kernel, dim3(n8 / 256), dim3(256), 0, stream, q, qb, n8);
  hipLaunchKernelGGL(cvt_kernel, dim3(n8 / 256), dim3(256), 0, stream, k, kb, n8);
  hipLaunchKernelGGL(wtr_kernel, dim3(8, 8), dim3(256), 0, stream, Wq, Wqt);
  hipLaunchKernelGGL(wtr_kernel, dim3(8, 8), dim3(256), 0, stream, Wk, Wkt);
  hipLaunchKernelGGL(wtr_kernel, dim3(8, 8), dim3(256), 0, stream, Wv, Wvt);
  hipLaunchKernelGGL(wtr_kernel, dim3(8, 8), dim3(256), 0, stream, Wo, Wot);

  const dim3 ggrid(DMODEL / 64, TOK / 128);  // (8, 64)
  hipLaunchKernelGGL((gemm_mfma<0>), ggrid, dim3(256), 0, stream, qb, Wqt, bq, 0.125f, qpb);
  hipLaunchKernelGGL((gemm_mfma<0>), ggrid, dim3(256), 0, stream, kb, Wkt, bk, 1.0f, kpb);
  hipLaunchKernelGGL((gemm_mfma<0>), ggrid, dim3(256), 0, stream, kpb, Wvt, bv, 1.0f, vpb);

  hipLaunchKernelGGL(vtr_kernel, dim3(16, 8, 8), dim3(256), 0, stream, vpb, vtb);

  hipLaunchKernelGGL(attn_mfma, dim3(NHEADS * 16 * NBATCH), dim3(256), 0, stream,
                     qpb, kpb, vtb, pos, qm, km, attnb);

  hipLaunchKernelGGL((gemm_mfma<1>), ggrid, dim3(256), 0, stream, attnb, Wot, bo, 1.0f, out);
}

// Round 6
// 231.852 us; speedup vs baseline: 3.7276x; 1.0074x over previous
//
#include <hip/hip_runtime.h>
#include <math.h>

// Problem constants: B=8, H=W=32, D=512, NH=8, DKH=DVH=64
#define TOK 8192
#define DMODEL 512
#define SEQ 1024
#define NHEADS 8
#define DH 64
#define NBATCH 8

typedef __attribute__((ext_vector_type(8))) short short8v;   // 8 bf16 = 4 VGPR
typedef __attribute__((ext_vector_type(4))) float f32x4;
typedef __attribute__((ext_vector_type(4))) int i32x4;

#define MFMA16(a, b, c) __builtin_amdgcn_mfma_f32_16x16x32_bf16(a, b, c, 0, 0, 0)

__device__ __forceinline__ unsigned short f2bf(float x) {
  union { float f; unsigned int u; } v; v.f = x;
  unsigned int r = v.u + 0x7fffu + ((v.u >> 16) & 1u);  // RNE
  return (unsigned short)(r >> 16);
}

// static-pattern cross-lane xor swap (BitMode ds_swizzle, and=0x1f)
template <int PAT>
__device__ __forceinline__ float swz(float v) {
  return __int_as_float(__builtin_amdgcn_ds_swizzle(__float_as_int(v), PAT));
}

// ---------------------------------------------------------------------------
// f32 -> bf16 elementwise (8 elems/thread)
// ---------------------------------------------------------------------------
__global__ __launch_bounds__(256) void cvt_kernel(const float* __restrict__ src,
                                                  unsigned short* __restrict__ dst,
                                                  int n8) {
  int i = blockIdx.x * 256 + threadIdx.x;
  if (i >= n8) return;
  const float4* s4 = reinterpret_cast<const float4*>(src);
  float4 a = s4[2 * (size_t)i], b = s4[2 * (size_t)i + 1];
  short8v o;
  o[0] = (short)f2bf(a.x); o[1] = (short)f2bf(a.y);
  o[2] = (short)f2bf(a.z); o[3] = (short)f2bf(a.w);
  o[4] = (short)f2bf(b.x); o[5] = (short)f2bf(b.y);
  o[6] = (short)f2bf(b.z); o[7] = (short)f2bf(b.w);
  *reinterpret_cast<short8v*>(dst + 8 * (size_t)i) = o;
}

// ---------------------------------------------------------------------------
// Weight transpose + convert: Wt[n][k] = bf16(W[k][n]), 512x512.
// ---------------------------------------------------------------------------
__global__ __launch_bounds__(256) void wtr_kernel(const float* __restrict__ W,
                                                  unsigned short* __restrict__ Wt) {
  __shared__ unsigned short tile[64][72];
  const int kt = blockIdx.x, nt = blockIdx.y;
  const int t = threadIdx.x, r = t >> 2, c0 = (t & 3) * 16;
  const float* src = W + (size_t)(kt * 64 + r) * 512 + nt * 64 + c0;
  short8v v0, v1;
#pragma unroll
  for (int e = 0; e < 4; ++e) {
    float4 f = *reinterpret_cast<const float4*>(src + e * 4);
    short* dstv = (e < 2) ? (short*)&v0 : (short*)&v1;
    dstv[(e & 1) * 4 + 0] = (short)f2bf(f.x);
    dstv[(e & 1) * 4 + 1] = (short)f2bf(f.y);
    dstv[(e & 1) * 4 + 2] = (short)f2bf(f.z);
    dstv[(e & 1) * 4 + 3] = (short)f2bf(f.w);
  }
  *reinterpret_cast<short8v*>(&tile[r][c0]) = v0;
  *reinterpret_cast<short8v*>(&tile[r][c0 + 8]) = v1;
  __syncthreads();
  short8v o0, o1;
#pragma unroll
  for (int e = 0; e < 8; ++e) o0[e] = (short)tile[c0 + e][r];
#pragma unroll
  for (int e = 0; e < 8; ++e) o1[e] = (short)tile[c0 + 8 + e][r];
  unsigned short* dst = Wt + (size_t)(nt * 64 + r) * 512 + kt * 64 + c0;
  *reinterpret_cast<short8v*>(dst) = o0;
  *reinterpret_cast<short8v*>(dst + 8) = o1;
}

// ---------------------------------------------------------------------------
// V transpose: vt[(b*8+h)*64 + d][j] = vp[b*1024 + j][h*64 + d] (bf16 in/out)
// ---------------------------------------------------------------------------
__global__ __launch_bounds__(256) void vtr_kernel(const unsigned short* __restrict__ vp,
                                                  unsigned short* __restrict__ vt) {
  __shared__ unsigned short tile[64][72];
  const int jt = blockIdx.x, hh = blockIdx.y, bb = blockIdx.z;
  const int t = threadIdx.x, r = t >> 2, c0 = (t & 3) * 16;
  const unsigned short* src = vp + (size_t)(bb * SEQ + jt * 64 + r) * DMODEL + hh * DH + c0;
  *reinterpret_cast<short8v*>(&tile[r][c0]) = *reinterpret_cast<const short8v*>(src);
  *reinterpret_cast<short8v*>(&tile[r][c0 + 8]) = *reinterpret_cast<const short8v*>(src + 8);
  __syncthreads();
  short8v o0, o1;
#pragma unroll
  for (int e = 0; e < 8; ++e) o0[e] = (short)tile[c0 + e][r];
#pragma unroll
  for (int e = 0; e < 8; ++e) o1[e] = (short)tile[c0 + 8 + e][r];
  unsigned short* dst = vt + (size_t)((bb * 8 + hh) * 64 + r) * SEQ + jt * 64 + c0;
  *reinterpret_cast<short8v*>(dst) = o0;
  *reinterpret_cast<short8v*>(dst + 8) = o1;
}

// ---------------------------------------------------------------------------
// MFMA GEMM: C[M,512] = (A[M,512] @ Wt^T + bias) * scale  (unchanged)
// ---------------------------------------------------------------------------
template <int OUTF32>
__global__ __launch_bounds__(256) void gemm_mfma(
    const unsigned short* __restrict__ A, const unsigned short* __restrict__ Wt,
    const float* __restrict__ bias, float scale, void* __restrict__ Cout) {
  __shared__ unsigned short Asl[128][72];
  __shared__ unsigned short Bsl[64][72];
  const int t = threadIdx.x;
  const int w = t >> 6, lane = t & 63, li = lane & 15, lg = lane >> 4;
  const int wr = w >> 1, wc = w & 1;
  const int rowBase = blockIdx.y * 128, colBase = blockIdx.x * 64;

  f32x4 zero4 = {0.f, 0.f, 0.f, 0.f};
  f32x4 acc[4][2];
#pragma unroll
  for (int mi = 0; mi < 4; ++mi)
#pragma unroll
    for (int nj = 0; nj < 2; ++nj) acc[mi][nj] = zero4;

  for (int k0 = 0; k0 < 512; k0 += 64) {
    {
      const int r = t >> 1, hf = (t & 1) * 32;
      const unsigned short* src = A + (size_t)(rowBase + r) * 512 + k0 + hf;
#pragma unroll
      for (int q = 0; q < 4; ++q)
        *reinterpret_cast<short8v*>(&Asl[r][hf + q * 8]) =
            *reinterpret_cast<const short8v*>(src + q * 8);
    }
    {
      const int r = t >> 2, q = (t & 3) * 16;
      const unsigned short* src = Wt + (size_t)(colBase + r) * 512 + k0 + q;
      *reinterpret_cast<short8v*>(&Bsl[r][q]) = *reinterpret_cast<const short8v*>(src);
      *reinterpret_cast<short8v*>(&Bsl[r][q + 8]) = *reinterpret_cast<const short8v*>(src + 8);
    }
    __syncthreads();
#pragma unroll
    for (int kk = 0; kk < 2; ++kk) {
      short8v af[4], bf[2];
#pragma unroll
      for (int mi = 0; mi < 4; ++mi)
        af[mi] = *reinterpret_cast<short8v*>(&Asl[wr * 64 + mi * 16 + li][kk * 32 + lg * 8]);
#pragma unroll
      for (int nj = 0; nj < 2; ++nj)
        bf[nj] = *reinterpret_cast<short8v*>(&Bsl[wc * 32 + nj * 16 + li][kk * 32 + lg * 8]);
#pragma unroll
      for (int mi = 0; mi < 4; ++mi)
#pragma unroll
        for (int nj = 0; nj < 2; ++nj) acc[mi][nj] = MFMA16(af[mi], bf[nj], acc[mi][nj]);
    }
    __syncthreads();
  }
#pragma unroll
  for (int nj = 0; nj < 2; ++nj) {
    const int col = colBase + wc * 32 + nj * 16 + li;
    const float bv = bias[col];
#pragma unroll
    for (int mi = 0; mi < 4; ++mi) {
#pragma unroll
      for (int r = 0; r < 4; ++r) {
        const int row = rowBase + wr * 64 + mi * 16 + lg * 4 + r;
        const float v = (acc[mi][nj][r] + bv) * scale;
        if (OUTF32)
          reinterpret_cast<float*>(Cout)[(size_t)row * 512 + col] = v;
        else
          reinterpret_cast<unsigned short*>(Cout)[(size_t)row * 512 + col] = f2bf(v);
      }
    }
  }
}

// ---------------------------------------------------------------------------
// Barrier-free MFMA flash attention, PERMUTED key mapping + prefetch.
// MFMA slot (n, li) computes key kbase + li*4 + n  (K B-frag loaded from row
// li*4+n). Consequences: pos loads are float4 (dense), kmask is one int4,
// each lane's 4 keys are consecutive, P lands in LDS in natural key order.
// Prefetch: V issued mid-iter, K/pos/km for kt+1 issued right after last use.
// ---------------------------------------------------------------------------
__global__ __launch_bounds__(256) void attn_mfma(
    const unsigned short* __restrict__ qp, const unsigned short* __restrict__ kp,
    const unsigned short* __restrict__ vt, const float* __restrict__ pos,
    const int* __restrict__ qmask, const int* __restrict__ kmask,
    unsigned short* __restrict__ outb) {
  const int wg = blockIdx.x;           // qtile + 16*b + 128*h
  const int h = wg >> 7, b = (wg >> 4) & 7, qtile = wg & 15;
  const int qbase = qtile * 64;
  const int t = threadIdx.x, w = t >> 6, lane = t & 63, li = lane & 15, lg = lane >> 4;
  const int wq = w * 16;

  __shared__ unsigned short P_lds[2][64][72];

  // Q fragments (A-operand): row wq+li, k-chunks lg*8
  const size_t qrow = (size_t)(b * SEQ + qbase + wq + li) * DMODEL + h * DH;
  const short8v qf0 = *reinterpret_cast<const short8v*>(qp + qrow + lg * 8);
  const short8v qf1 = *reinterpret_cast<const short8v*>(qp + qrow + 32 + lg * 8);

  int qmr[4];
#pragma unroll
  for (int r = 0; r < 4; ++r)
    qmr[r] = qmask[b * SEQ + qbase + wq + lg * 4 + r];

  f32x4 zero4 = {0.f, 0.f, 0.f, 0.f};
  f32x4 acc_o[4];
#pragma unroll
  for (int n = 0; n < 4; ++n) acc_o[n] = zero4;
  float m[4], l[4];
#pragma unroll
  for (int r = 0; r < 4; ++r) { m[r] = -3e38f; l[r] = 0.f; }

  // hoisted bases
  const f32x4* pos4 =
      reinterpret_cast<const f32x4*>(pos) +
      (size_t)(b * SEQ + qbase + wq + lg * 4) * (SEQ / 4) + li;      // + r*(SEQ/4) + kt*16
  const i32x4* km4 = reinterpret_cast<const i32x4*>(kmask) + (b * SEQ) / 4 + li;  // + kt*16
  const unsigned short* kpl =
      kp + (size_t)(b * SEQ + li * 4) * DMODEL + h * DH + lg * 8;    // + (kbase+n)*DMODEL
  const unsigned short* vtl =
      vt + (size_t)((b * 8 + h) * 64 + li) * SEQ + lg * 8;           // + n*16*SEQ + kbase

  // ---- prologue: prefetch kt=0 K, pos, kmask
  short8v kf[4][2];
#pragma unroll
  for (int n = 0; n < 4; ++n) {
    const unsigned short* kr = kpl + (size_t)n * DMODEL;
    kf[n][0] = *reinterpret_cast<const short8v*>(kr);
    kf[n][1] = *reinterpret_cast<const short8v*>(kr + 32);
  }
  f32x4 pvv[4];
#pragma unroll
  for (int r = 0; r < 4; ++r) pvv[r] = pos4[(size_t)r * (SEQ / 4)];
  i32x4 kmv = km4[0];

  for (int kt = 0; kt < 16; ++kt) {
    const int kbase = kt * 64;

    // ---- QK^T: s[n] = S[rows wq+lg*4+r][key-slot (n,li) = kbase+li*4+n]
    f32x4 s[4];
    __builtin_amdgcn_s_setprio(1);
#pragma unroll
    for (int n = 0; n < 4; ++n) {
      s[n] = MFMA16(qf0, kf[n][0], zero4);
      s[n] = MFMA16(qf1, kf[n][1], s[n]);
    }
    __builtin_amdgcn_s_setprio(0);

    // ---- prefetch next-kt K (kf consumed above; WAR keeps order)
    if (kt < 15) {
#pragma unroll
      for (int n = 0; n < 4; ++n) {
        const unsigned short* kr = kpl + (size_t)(kbase + 64 + n) * DMODEL;
        kf[n][0] = *reinterpret_cast<const short8v*>(kr);
        kf[n][1] = *reinterpret_cast<const short8v*>(kr + 32);
      }
    }

    // ---- issue V loads for current kt (consumed after softmax)
    short8v vf[4][2];
#pragma unroll
    for (int n = 0; n < 4; ++n) {
      const unsigned short* vr = vtl + (size_t)(n * 16) * SEQ + kbase;
      vf[n][0] = *reinterpret_cast<const short8v*>(vr);
      vf[n][1] = *reinterpret_cast<const short8v*>(vr + 32);
    }

    // ---- scores + mask (uses pvv/kmv of current kt)
    float x[4][4];  // [n][r]
#pragma unroll
    for (int n = 0; n < 4; ++n)
#pragma unroll
      for (int r = 0; r < 4; ++r) {
        float xx = s[n][r] + pvv[r][n];
        if ((qmr[r] != 0) != (kmv[n] != 0)) xx = -1e30f;
        x[n][r] = xx;
      }

    // ---- prefetch next-kt pos/kmask
    if (kt < 15) {
#pragma unroll
      for (int r = 0; r < 4; ++r) pvv[r] = pos4[(size_t)r * (SEQ / 4) + (kt + 1) * 16];
      kmv = km4[(kt + 1) * 16];
    }

    // ---- online softmax: per-lane 4-key partials, then xor-swizzle over li
    float pm[4];
#pragma unroll
    for (int r = 0; r < 4; ++r)
      pm[r] = fmaxf(fmaxf(x[0][r], x[1][r]), fmaxf(x[2][r], x[3][r]));
#pragma unroll
    for (int r = 0; r < 4; ++r) {
      pm[r] = fmaxf(pm[r], swz<0x041F>(pm[r]));
      pm[r] = fmaxf(pm[r], swz<0x081F>(pm[r]));
      pm[r] = fmaxf(pm[r], swz<0x101F>(pm[r]));
      pm[r] = fmaxf(pm[r], swz<0x201F>(pm[r]));
    }
    float rs[4], ps[4];
#pragma unroll
    for (int r = 0; r < 4; ++r) {
      const float mn = fmaxf(m[r], pm[r]);
      rs[r] = __expf(m[r] - mn);
      m[r] = mn;
    }
#pragma unroll
    for (int n = 0; n < 4; ++n)
#pragma unroll
      for (int r = 0; r < 4; ++r) x[n][r] = __expf(x[n][r] - m[r]);
#pragma unroll
    for (int r = 0; r < 4; ++r) {
      ps[r] = (x[0][r] + x[1][r]) + (x[2][r] + x[3][r]);
      ps[r] += swz<0x041F>(ps[r]);
      ps[r] += swz<0x081F>(ps[r]);
      ps[r] += swz<0x101F>(ps[r]);
      ps[r] += swz<0x201F>(ps[r]);
      l[r] = l[r] * rs[r] + ps[r];
    }
#pragma unroll
    for (int n = 0; n < 4; ++n)
#pragma unroll
      for (int r = 0; r < 4; ++r) acc_o[n][r] *= rs[r];

    // ---- P -> LDS (natural key order; one 8B write per r), no barrier
    unsigned short (*P)[72] = P_lds[kt & 1];
#pragma unroll
    for (int r = 0; r < 4; ++r) {
      unsigned int lo = (unsigned int)f2bf(x[0][r]) | ((unsigned int)f2bf(x[1][r]) << 16);
      unsigned int hi = (unsigned int)f2bf(x[2][r]) | ((unsigned int)f2bf(x[3][r]) << 16);
      *reinterpret_cast<uint2*>(&P[wq + lg * 4 + r][li * 4]) = make_uint2(lo, hi);
    }
    asm volatile("s_waitcnt lgkmcnt(0)" ::: "memory");
    __builtin_amdgcn_sched_barrier(0);
    const short8v pf0 = *reinterpret_cast<short8v*>(&P[wq + li][lg * 8]);
    const short8v pf1 = *reinterpret_cast<short8v*>(&P[wq + li][32 + lg * 8]);

    // ---- PV
    __builtin_amdgcn_s_setprio(1);
#pragma unroll
    for (int n = 0; n < 4; ++n) {
      acc_o[n] = MFMA16(pf0, vf[n][0], acc_o[n]);
      acc_o[n] = MFMA16(pf1, vf[n][1], acc_o[n]);
    }
    __builtin_amdgcn_s_setprio(0);
  }

  // ---- epilogue
  float inv[4];
#pragma unroll
  for (int r = 0; r < 4; ++r) inv[r] = 1.f / l[r];
  unsigned short* ob = outb + (size_t)(b * SEQ + qbase + wq) * DMODEL + h * DH;
#pragma unroll
  for (int n = 0; n < 4; ++n)
#pragma unroll
    for (int r = 0; r < 4; ++r)
      ob[(size_t)(lg * 4 + r) * DMODEL + n * 16 + li] = f2bf(acc_o[n][r] * inv[r]);
}

// ---------------------------------------------------------------------------
extern "C" void kernel_launch(void* const* d_in, const int* in_sizes, int n_in,
                              void* d_out, int out_size, void* d_ws, size_t ws_size,
                              hipStream_t stream) {
  const float* q   = (const float*)d_in[0];
  const float* k   = (const float*)d_in[1];
  const int*   qm  = (const int*)d_in[2];
  const int*   km  = (const int*)d_in[3];
  const float* pos = (const float*)d_in[4];
  const float* Wq  = (const float*)d_in[5];
  const float* bq  = (const float*)d_in[6];
  const float* Wk  = (const float*)d_in[7];
  const float* bk  = (const float*)d_in[8];
  const float* Wv  = (const float*)d_in[9];
  const float* bv  = (const float*)d_in[10];
  const float* Wo  = (const float*)d_in[11];
  const float* bo  = (const float*)d_in[12];
  float* out = (float*)d_out;

  char* ws = (char*)d_ws;
  const size_t MB8 = (size_t)TOK * DMODEL * 2;  // 8 MB per bf16 [8192][512]
  unsigned short* qb    = (unsigned short*)(ws);
  unsigned short* kb    = (unsigned short*)(ws + MB8);
  unsigned short* qpb   = (unsigned short*)(ws + 2 * MB8);
  unsigned short* kpb   = (unsigned short*)(ws + 3 * MB8);
  unsigned short* vpb   = (unsigned short*)(ws + 4 * MB8);
  unsigned short* attnb = (unsigned short*)(ws + 5 * MB8);
  unsigned short* vtb   = (unsigned short*)(ws + 6 * MB8);
  unsigned short* Wqt   = (unsigned short*)(ws + 7 * MB8);
  unsigned short* Wkt   = Wqt + (size_t)512 * 512;
  unsigned short* Wvt   = Wkt + (size_t)512 * 512;
  unsigned short* Wot   = Wvt + (size_t)512 * 512;

  const int n8 = TOK * DMODEL / 8;
  hipLaunchKernelGGL(cvt_kernel, dim3(n8 / 256), dim3(256), 0, stream, q, qb, n8);
  hipLaunchKernelGGL(cvt_kernel, dim3(n8 / 256), dim3(256), 0, stream, k, kb, n8);
  hipLaunchKernelGGL(wtr_kernel, dim3(8, 8), dim3(256), 0, stream, Wq, Wqt);
  hipLaunchKernelGGL(wtr_kernel, dim3(8, 8), dim3(256), 0, stream, Wk, Wkt);
  hipLaunchKernelGGL(wtr_kernel, dim3(8, 8), dim3(256), 0, stream, Wv, Wvt);
  hipLaunchKernelGGL(wtr_kernel, dim3(8, 8), dim3(256), 0, stream, Wo, Wot);

  const dim3 ggrid(DMODEL / 64, TOK / 128);  // (8, 64)
  hipLaunchKernelGGL((gemm_mfma<0>), ggrid, dim3(256), 0, stream, qb, Wqt, bq, 0.125f, qpb);
  hipLaunchKernelGGL((gemm_mfma<0>), ggrid, dim3(256), 0, stream, kb, Wkt, bk, 1.0f, kpb);
  hipLaunchKernelGGL((gemm_mfma<0>), ggrid, dim3(256), 0, stream, kpb, Wvt, bv, 1.0f, vpb);

  hipLaunchKernelGGL(vtr_kernel, dim3(16, 8, 8), dim3(256), 0, stream, vpb, vtb);

  hipLaunchKernelGGL(attn_mfma, dim3(NHEADS * 16 * NBATCH), dim3(256), 0, stream,
                     qpb, kpb, vtb, pos, qm, km, attnb);

  hipLaunchKernelGGL((gemm_mfma<1>), ggrid, dim3(256), 0, stream, attnb, Wot, bo, 1.0f, out);
}

// Round 7
// 152.471 us; speedup vs baseline: 5.6683x; 1.5206x over previous
//
#include <hip/hip_runtime.h>
#include <math.h>

// Problem constants: B=8, H=W=32, D=512, NH=8, DKH=DVH=64
#define TOK 8192
#define DMODEL 512
#define SEQ 1024
#define NHEADS 8
#define DH 64
#define NBATCH 8

typedef __attribute__((ext_vector_type(8))) short short8v;   // 8 bf16 = 4 VGPR
typedef __attribute__((ext_vector_type(4))) float f32x4;
typedef __attribute__((ext_vector_type(4))) int i32x4;

#define MFMA16(a, b, c) __builtin_amdgcn_mfma_f32_16x16x32_bf16(a, b, c, 0, 0, 0)

__device__ __forceinline__ unsigned short f2bf(float x) {
  union { float f; unsigned int u; } v; v.f = x;
  unsigned int r = v.u + 0x7fffu + ((v.u >> 16) & 1u);  // RNE
  return (unsigned short)(r >> 16);
}

// ---------------------------------------------------------------------------
// f32 -> bf16 elementwise (8 elems/thread)
// ---------------------------------------------------------------------------
__global__ __launch_bounds__(256) void cvt_kernel(const float* __restrict__ src,
                                                  unsigned short* __restrict__ dst,
                                                  int n8) {
  int i = blockIdx.x * 256 + threadIdx.x;
  if (i >= n8) return;
  const float4* s4 = reinterpret_cast<const float4*>(src);
  float4 a = s4[2 * (size_t)i], b = s4[2 * (size_t)i + 1];
  short8v o;
  o[0] = (short)f2bf(a.x); o[1] = (short)f2bf(a.y);
  o[2] = (short)f2bf(a.z); o[3] = (short)f2bf(a.w);
  o[4] = (short)f2bf(b.x); o[5] = (short)f2bf(b.y);
  o[6] = (short)f2bf(b.z); o[7] = (short)f2bf(b.w);
  *reinterpret_cast<short8v*>(dst + 8 * (size_t)i) = o;
}

// ---------------------------------------------------------------------------
// Weight transpose + convert: Wt[n][k] = bf16(W[k][n]), 512x512.
// ---------------------------------------------------------------------------
__global__ __launch_bounds__(256) void wtr_kernel(const float* __restrict__ W,
                                                  unsigned short* __restrict__ Wt) {
  __shared__ unsigned short tile[64][72];
  const int kt = blockIdx.x, nt = blockIdx.y;
  const int t = threadIdx.x, r = t >> 2, c0 = (t & 3) * 16;
  const float* src = W + (size_t)(kt * 64 + r) * 512 + nt * 64 + c0;
  short8v v0, v1;
#pragma unroll
  for (int e = 0; e < 4; ++e) {
    float4 f = *reinterpret_cast<const float4*>(src + e * 4);
    short* dstv = (e < 2) ? (short*)&v0 : (short*)&v1;
    dstv[(e & 1) * 4 + 0] = (short)f2bf(f.x);
    dstv[(e & 1) * 4 + 1] = (short)f2bf(f.y);
    dstv[(e & 1) * 4 + 2] = (short)f2bf(f.z);
    dstv[(e & 1) * 4 + 3] = (short)f2bf(f.w);
  }
  *reinterpret_cast<short8v*>(&tile[r][c0]) = v0;
  *reinterpret_cast<short8v*>(&tile[r][c0 + 8]) = v1;
  __syncthreads();
  short8v o0, o1;
#pragma unroll
  for (int e = 0; e < 8; ++e) o0[e] = (short)tile[c0 + e][r];
#pragma unroll
  for (int e = 0; e < 8; ++e) o1[e] = (short)tile[c0 + 8 + e][r];
  unsigned short* dst = Wt + (size_t)(nt * 64 + r) * 512 + kt * 64 + c0;
  *reinterpret_cast<short8v*>(dst) = o0;
  *reinterpret_cast<short8v*>(dst + 8) = o1;
}

// ---------------------------------------------------------------------------
// V transpose: vt[(b*8+h)*64 + d][j] = vp[b*1024 + j][h*64 + d] (bf16 in/out)
// ---------------------------------------------------------------------------
__global__ __launch_bounds__(256) void vtr_kernel(const unsigned short* __restrict__ vp,
                                                  unsigned short* __restrict__ vt) {
  __shared__ unsigned short tile[64][72];
  const int jt = blockIdx.x, hh = blockIdx.y, bb = blockIdx.z;
  const int t = threadIdx.x, r = t >> 2, c0 = (t & 3) * 16;
  const unsigned short* src = vp + (size_t)(bb * SEQ + jt * 64 + r) * DMODEL + hh * DH + c0;
  *reinterpret_cast<short8v*>(&tile[r][c0]) = *reinterpret_cast<const short8v*>(src);
  *reinterpret_cast<short8v*>(&tile[r][c0 + 8]) = *reinterpret_cast<const short8v*>(src + 8);
  __syncthreads();
  short8v o0, o1;
#pragma unroll
  for (int e = 0; e < 8; ++e) o0[e] = (short)tile[c0 + e][r];
#pragma unroll
  for (int e = 0; e < 8; ++e) o1[e] = (short)tile[c0 + 8 + e][r];
  unsigned short* dst = vt + (size_t)((bb * 8 + hh) * 64 + r) * SEQ + jt * 64 + c0;
  *reinterpret_cast<short8v*>(dst) = o0;
  *reinterpret_cast<short8v*>(dst + 8) = o1;
}

// ---------------------------------------------------------------------------
// MFMA GEMM: C[M,512] = (A[M,512] @ Wt^T + bias) * scale  (unchanged)
// ---------------------------------------------------------------------------
template <int OUTF32>
__global__ __launch_bounds__(256) void gemm_mfma(
    const unsigned short* __restrict__ A, const unsigned short* __restrict__ Wt,
    const float* __restrict__ bias, float scale, void* __restrict__ Cout) {
  __shared__ unsigned short Asl[128][72];
  __shared__ unsigned short Bsl[64][72];
  const int t = threadIdx.x;
  const int w = t >> 6, lane = t & 63, li = lane & 15, lg = lane >> 4;
  const int wr = w >> 1, wc = w & 1;
  const int rowBase = blockIdx.y * 128, colBase = blockIdx.x * 64;

  f32x4 zero4 = {0.f, 0.f, 0.f, 0.f};
  f32x4 acc[4][2];
#pragma unroll
  for (int mi = 0; mi < 4; ++mi)
#pragma unroll
    for (int nj = 0; nj < 2; ++nj) acc[mi][nj] = zero4;

  for (int k0 = 0; k0 < 512; k0 += 64) {
    {
      const int r = t >> 1, hf = (t & 1) * 32;
      const unsigned short* src = A + (size_t)(rowBase + r) * 512 + k0 + hf;
#pragma unroll
      for (int q = 0; q < 4; ++q)
        *reinterpret_cast<short8v*>(&Asl[r][hf + q * 8]) =
            *reinterpret_cast<const short8v*>(src + q * 8);
    }
    {
      const int r = t >> 2, q = (t & 3) * 16;
      const unsigned short* src = Wt + (size_t)(colBase + r) * 512 + k0 + q;
      *reinterpret_cast<short8v*>(&Bsl[r][q]) = *reinterpret_cast<const short8v*>(src);
      *reinterpret_cast<short8v*>(&Bsl[r][q + 8]) = *reinterpret_cast<const short8v*>(src + 8);
    }
    __syncthreads();
#pragma unroll
    for (int kk = 0; kk < 2; ++kk) {
      short8v af[4], bf[2];
#pragma unroll
      for (int mi = 0; mi < 4; ++mi)
        af[mi] = *reinterpret_cast<short8v*>(&Asl[wr * 64 + mi * 16 + li][kk * 32 + lg * 8]);
#pragma unroll
      for (int nj = 0; nj < 2; ++nj)
        bf[nj] = *reinterpret_cast<short8v*>(&Bsl[wc * 32 + nj * 16 + li][kk * 32 + lg * 8]);
#pragma unroll
      for (int mi = 0; mi < 4; ++mi)
#pragma unroll
        for (int nj = 0; nj < 2; ++nj) acc[mi][nj] = MFMA16(af[mi], bf[nj], acc[mi][nj]);
    }
    __syncthreads();
  }
#pragma unroll
  for (int nj = 0; nj < 2; ++nj) {
    const int col = colBase + wc * 32 + nj * 16 + li;
    const float bv = bias[col];
#pragma unroll
    for (int mi = 0; mi < 4; ++mi) {
#pragma unroll
      for (int r = 0; r < 4; ++r) {
        const int row = rowBase + wr * 64 + mi * 16 + lg * 4 + r;
        const float v = (acc[mi][nj][r] + bv) * scale;
        if (OUTF32)
          reinterpret_cast<float*>(Cout)[(size_t)row * 512 + col] = v;
        else
          reinterpret_cast<unsigned short*>(Cout)[(size_t)row * 512 + col] = f2bf(v);
      }
    }
  }
}

// ---------------------------------------------------------------------------
// Traffic-shared MFMA flash attention.
// Block = (b, h, 128-q chunk): 512 thr = 8 waves x 16 q-rows. K-tile and
// V^T-tile (8 KB each) staged ONCE per block into dbuf padded LDS [64][72]
// (was loaded per-wave from global -> ~3x less L1/L2 traffic). SWAPPED QK^T
// (mfma(K,Q) -> S^T): keys per lg, queries per li -> pos/kmask loads stay
// dense float4/int4, softmax reduce = shfl_xor(16,32), m/l per-lane scalars.
// T14: stage loads issued at iter top, ds_writes after PV, 1 barrier/iter.
// blockIdx = qc*64 + h*8 + b: blocks sharing pos slice (same b,qc) and blocks
// sharing K/V head (same b,h) both land on one XCD -> L2-served reuse.
// ---------------------------------------------------------------------------
__global__ __launch_bounds__(512, 4) void attn_mfma(
    const unsigned short* __restrict__ qp, const unsigned short* __restrict__ kp,
    const unsigned short* __restrict__ vt, const float* __restrict__ pos,
    const int* __restrict__ qmask, const int* __restrict__ kmask,
    unsigned short* __restrict__ outb) {
  const int bx = blockIdx.x;
  const int qc = bx >> 6, h = (bx >> 3) & 7, b = bx & 7;
  const int t = threadIdx.x, w = t >> 6, lane = t & 63, li = lane & 15, lg = lane >> 4;
  const int qrow = qc * 128 + w * 16;  // wave's query base within batch

  __shared__ unsigned short Kl[2][64 * 72];  // [key][dim], padded
  __shared__ unsigned short Vl[2][64 * 72];  // [dim][key] (V^T), padded
  __shared__ unsigned short Pl[8][16 * 72];  // per-wave P [query][key]

  // Q as B-frag: query = qrow + li
  const size_t qg = (size_t)(b * SEQ + qrow + li) * DMODEL + h * DH;
  const short8v qf0 = *reinterpret_cast<const short8v*>(qp + qg + lg * 8);
  const short8v qf1 = *reinterpret_cast<const short8v*>(qp + qg + 32 + lg * 8);
  const int qmv = qmask[b * SEQ + qrow + li];

  f32x4 zero4 = {0.f, 0.f, 0.f, 0.f};
  f32x4 acc_o[4];
#pragma unroll
  for (int n = 0; n < 4; ++n) acc_o[n] = zero4;
  float m = -3e38f, l = 0.f;

  // staging: thread t covers tile row t>>3, 8-short chunk t&7
  const int srow = t >> 3, schk = (t & 7) * 8;
  const unsigned short* kgp = kp + (size_t)(b * SEQ + srow) * DMODEL + h * DH + schk;
  const unsigned short* vgp = vt + ((size_t)((b * 8 + h) * 64) + srow) * SEQ + schk;
  const int sldst = srow * 72 + schk;

  // pos/km bases (dense per-lane vectors thanks to swapped layout)
  const float* posb = pos + (size_t)(b * SEQ + qrow + li) * SEQ;
  const int* kmb = kmask + b * SEQ;

  // prologue: stage tile kt=0
  {
    short8v kr = *reinterpret_cast<const short8v*>(kgp);
    short8v vr = *reinterpret_cast<const short8v*>(vgp);
    *reinterpret_cast<short8v*>(&Kl[0][sldst]) = kr;
    *reinterpret_cast<short8v*>(&Vl[0][sldst]) = vr;
  }
  __syncthreads();

  int buf = 0;
  for (int kt = 0; kt < 16; ++kt) {
    const int kbase = kt * 64;

    // issue next-tile staging loads early (consumed at iter end: T14)
    short8v kr, vr;
    if (kt < 15) {
      kr = *reinterpret_cast<const short8v*>(kgp + (size_t)(kbase + 64) * DMODEL);
      vr = *reinterpret_cast<const short8v*>(vgp + kbase + 64);
    }

    // pos/km for current tile: component r = key kbase+n*16+lg*4+r, query qrow+li
    f32x4 pvn[4];
    i32x4 kmn[4];
#pragma unroll
    for (int n = 0; n < 4; ++n) {
      pvn[n] = *reinterpret_cast<const f32x4*>(posb + kbase + n * 16 + lg * 4);
      kmn[n] = *reinterpret_cast<const i32x4*>(kmb + kbase + n * 16 + lg * 4);
    }

    // ---- swapped QK^T: x4[n][r] = S[key kbase+n*16+lg*4+r][query qrow+li]
    f32x4 x4[4];
    __builtin_amdgcn_s_setprio(1);
#pragma unroll
    for (int n = 0; n < 4; ++n) {
      short8v kfa = *reinterpret_cast<short8v*>(&Kl[buf][(n * 16 + li) * 72 + lg * 8]);
      short8v kfb = *reinterpret_cast<short8v*>(&Kl[buf][(n * 16 + li) * 72 + 32 + lg * 8]);
      x4[n] = MFMA16(kfa, qf0, zero4);
      x4[n] = MFMA16(kfb, qf1, x4[n]);
    }
    __builtin_amdgcn_s_setprio(0);

    // ---- scores + mask + online softmax (query per li lane)
    float x[4][4];
    float tm = -3e38f;
#pragma unroll
    for (int n = 0; n < 4; ++n)
#pragma unroll
      for (int r = 0; r < 4; ++r) {
        float xx = x4[n][r] + pvn[n][r];
        if ((qmv != 0) != (kmn[n][r] != 0)) xx = -1e30f;
        x[n][r] = xx;
        tm = fmaxf(tm, xx);
      }
    tm = fmaxf(tm, __shfl_xor(tm, 16));
    tm = fmaxf(tm, __shfl_xor(tm, 32));
    const float mn = fmaxf(m, tm);
    const float rs = __expf(m - mn);
    m = mn;
    float psum = 0.f;
#pragma unroll
    for (int n = 0; n < 4; ++n)
#pragma unroll
      for (int r = 0; r < 4; ++r) {
        const float p = __expf(x[n][r] - m);
        x[n][r] = p;
        psum += p;
      }
    psum += __shfl_xor(psum, 16);
    psum += __shfl_xor(psum, 32);
    l = l * rs + psum;
    float rsb[4];
#pragma unroll
    for (int r = 0; r < 4; ++r) rsb[r] = __shfl(rs, lg * 4 + r, 16);
#pragma unroll
    for (int n = 0; n < 4; ++n)
#pragma unroll
      for (int r = 0; r < 4; ++r) acc_o[n][r] *= rsb[r];

    // ---- P^T -> per-wave LDS (query-row layout), wave-local fence
#pragma unroll
    for (int n = 0; n < 4; ++n) {
      unsigned int lo = (unsigned int)f2bf(x[n][0]) | ((unsigned int)f2bf(x[n][1]) << 16);
      unsigned int hi = (unsigned int)f2bf(x[n][2]) | ((unsigned int)f2bf(x[n][3]) << 16);
      *reinterpret_cast<uint2*>(&Pl[w][li * 72 + n * 16 + lg * 4]) = make_uint2(lo, hi);
    }
    asm volatile("s_waitcnt lgkmcnt(0)" ::: "memory");
    __builtin_amdgcn_sched_barrier(0);
    const short8v pf0 = *reinterpret_cast<short8v*>(&Pl[w][li * 72 + lg * 8]);
    const short8v pf1 = *reinterpret_cast<short8v*>(&Pl[w][li * 72 + 32 + lg * 8]);

    // ---- PV from staged V^T tile
    __builtin_amdgcn_s_setprio(1);
#pragma unroll
    for (int n = 0; n < 4; ++n) {
      short8v vfa = *reinterpret_cast<short8v*>(&Vl[buf][(n * 16 + li) * 72 + lg * 8]);
      short8v vfb = *reinterpret_cast<short8v*>(&Vl[buf][(n * 16 + li) * 72 + 32 + lg * 8]);
      acc_o[n] = MFMA16(pf0, vfa, acc_o[n]);
      acc_o[n] = MFMA16(pf1, vfb, acc_o[n]);
    }
    __builtin_amdgcn_s_setprio(0);

    // ---- write staged regs into the other buffer, then block barrier
    if (kt < 15) {
      *reinterpret_cast<short8v*>(&Kl[buf ^ 1][sldst]) = kr;
      *reinterpret_cast<short8v*>(&Vl[buf ^ 1][sldst]) = vr;
      __syncthreads();
      buf ^= 1;
    }
  }

  // ---- epilogue: divide by l (per query), write bf16 head-concatenated
  const float linv = 1.f / l;
  float lb[4];
#pragma unroll
  for (int r = 0; r < 4; ++r) lb[r] = __shfl(linv, lg * 4 + r, 16);
  unsigned short* ob = outb + (size_t)(b * SEQ + qrow) * DMODEL + h * DH;
#pragma unroll
  for (int n = 0; n < 4; ++n)
#pragma unroll
    for (int r = 0; r < 4; ++r)
      ob[(size_t)(lg * 4 + r) * DMODEL + n * 16 + li] = f2bf(acc_o[n][r] * lb[r]);
}

// ---------------------------------------------------------------------------
extern "C" void kernel_launch(void* const* d_in, const int* in_sizes, int n_in,
                              void* d_out, int out_size, void* d_ws, size_t ws_size,
                              hipStream_t stream) {
  const float* q   = (const float*)d_in[0];
  const float* k   = (const float*)d_in[1];
  const int*   qm  = (const int*)d_in[2];
  const int*   km  = (const int*)d_in[3];
  const float* pos = (const float*)d_in[4];
  const float* Wq  = (const float*)d_in[5];
  const float* bq  = (const float*)d_in[6];
  const float* Wk  = (const float*)d_in[7];
  const float* bk  = (const float*)d_in[8];
  const float* Wv  = (const float*)d_in[9];
  const float* bv  = (const float*)d_in[10];
  const float* Wo  = (const float*)d_in[11];
  const float* bo  = (const float*)d_in[12];
  float* out = (float*)d_out;

  char* ws = (char*)d_ws;
  const size_t MB8 = (size_t)TOK * DMODEL * 2;  // 8 MB per bf16 [8192][512]
  unsigned short* qb    = (unsigned short*)(ws);
  unsigned short* kb    = (unsigned short*)(ws + MB8);
  unsigned short* qpb   = (unsigned short*)(ws + 2 * MB8);
  unsigned short* kpb   = (unsigned short*)(ws + 3 * MB8);
  unsigned short* vpb   = (unsigned short*)(ws + 4 * MB8);
  unsigned short* attnb = (unsigned short*)(ws + 5 * MB8);
  unsigned short* vtb   = (unsigned short*)(ws + 6 * MB8);
  unsigned short* Wqt   = (unsigned short*)(ws + 7 * MB8);
  unsigned short* Wkt   = Wqt + (size_t)512 * 512;
  unsigned short* Wvt   = Wkt + (size_t)512 * 512;
  unsigned short* Wot   = Wvt + (size_t)512 * 512;

  const int n8 = TOK * DMODEL / 8;
  hipLaunchKernelGGL(cvt_kernel, dim3(n8 / 256), dim3(256), 0, stream, q, qb, n8);
  hipLaunchKernelGGL(cvt_kernel, dim3(n8 / 256), dim3(256), 0, stream, k, kb, n8);
  hipLaunchKernelGGL(wtr_kernel, dim3(8, 8), dim3(256), 0, stream, Wq, Wqt);
  hipLaunchKernelGGL(wtr_kernel, dim3(8, 8), dim3(256), 0, stream, Wk, Wkt);
  hipLaunchKernelGGL(wtr_kernel, dim3(8, 8), dim3(256), 0, stream, Wv, Wvt);
  hipLaunchKernelGGL(wtr_kernel, dim3(8, 8), dim3(256), 0, stream, Wo, Wot);

  const dim3 ggrid(DMODEL / 64, TOK / 128);  // (8, 64)
  hipLaunchKernelGGL((gemm_mfma<0>), ggrid, dim3(256), 0, stream, qb, Wqt, bq, 0.125f, qpb);
  hipLaunchKernelGGL((gemm_mfma<0>), ggrid, dim3(256), 0, stream, kb, Wkt, bk, 1.0f, kpb);
  hipLaunchKernelGGL((gemm_mfma<0>), ggrid, dim3(256), 0, stream, kpb, Wvt, bv, 1.0f, vpb);

  hipLaunchKernelGGL(vtr_kernel, dim3(16, 8, 8), dim3(256), 0, stream, vpb, vtb);

  // grid 512: bx = qc*64 + h*8 + b
  hipLaunchKernelGGL(attn_mfma, dim3(512), dim3(512), 0, stream,
                     qpb, kpb, vtb, pos, qm, km, attnb);

  hipLaunchKernelGGL((gemm_mfma<1>), ggrid, dim3(256), 0, stream, attnb, Wot, bo, 1.0f, out);
}

// Round 8
// 144.358 us; speedup vs baseline: 5.9869x; 1.0562x over previous
//
#include <hip/hip_runtime.h>
#include <math.h>

// Problem constants: B=8, H=W=32, D=512, NH=8, DKH=DVH=64
#define TOK 8192
#define DMODEL 512
#define SEQ 1024
#define NHEADS 8
#define DH 64
#define NBATCH 8

typedef __attribute__((ext_vector_type(8))) short short8v;   // 8 bf16 = 4 VGPR
typedef __attribute__((ext_vector_type(4))) float f32x4;
typedef __attribute__((ext_vector_type(4))) int i32x4;

#define MFMA16(a, b, c) __builtin_amdgcn_mfma_f32_16x16x32_bf16(a, b, c, 0, 0, 0)

__device__ __forceinline__ unsigned short f2bf(float x) {
  union { float f; unsigned int u; } v; v.f = x;
  unsigned int r = v.u + 0x7fffu + ((v.u >> 16) & 1u);  // RNE
  return (unsigned short)(r >> 16);
}

// ---------------------------------------------------------------------------
// Weight transpose + convert: Wt[n][k] = bf16(W[k][n]), 512x512. 4 matrices
// in one dispatch (blockIdx.z selects).
// ---------------------------------------------------------------------------
__global__ __launch_bounds__(256) void wtr4_kernel(
    const float* __restrict__ W0, const float* __restrict__ W1,
    const float* __restrict__ W2, const float* __restrict__ W3,
    unsigned short* __restrict__ T0, unsigned short* __restrict__ T1,
    unsigned short* __restrict__ T2, unsigned short* __restrict__ T3) {
  __shared__ unsigned short tile[64][72];
  const int z = blockIdx.z;
  const float* W = (z == 0) ? W0 : (z == 1) ? W1 : (z == 2) ? W2 : W3;
  unsigned short* Wt = (z == 0) ? T0 : (z == 1) ? T1 : (z == 2) ? T2 : T3;
  const int kt = blockIdx.x, nt = blockIdx.y;
  const int t = threadIdx.x, r = t >> 2, c0 = (t & 3) * 16;
  const float* src = W + (size_t)(kt * 64 + r) * 512 + nt * 64 + c0;
  short8v v0, v1;
#pragma unroll
  for (int e = 0; e < 4; ++e) {
    float4 f = *reinterpret_cast<const float4*>(src + e * 4);
    short* dstv = (e < 2) ? (short*)&v0 : (short*)&v1;
    dstv[(e & 1) * 4 + 0] = (short)f2bf(f.x);
    dstv[(e & 1) * 4 + 1] = (short)f2bf(f.y);
    dstv[(e & 1) * 4 + 2] = (short)f2bf(f.z);
    dstv[(e & 1) * 4 + 3] = (short)f2bf(f.w);
  }
  *reinterpret_cast<short8v*>(&tile[r][c0]) = v0;
  *reinterpret_cast<short8v*>(&tile[r][c0 + 8]) = v1;
  __syncthreads();
  short8v o0, o1;
#pragma unroll
  for (int e = 0; e < 8; ++e) o0[e] = (short)tile[c0 + e][r];
#pragma unroll
  for (int e = 0; e < 8; ++e) o1[e] = (short)tile[c0 + 8 + e][r];
  unsigned short* dst = Wt + (size_t)(nt * 64 + r) * 512 + kt * 64 + c0;
  *reinterpret_cast<short8v*>(dst) = o0;
  *reinterpret_cast<short8v*>(dst + 8) = o1;
}

// ---------------------------------------------------------------------------
// V transpose: vt[(b*8+h)*64 + d][j] = vp[b*1024 + j][h*64 + d] (bf16 in/out)
// ---------------------------------------------------------------------------
__global__ __launch_bounds__(256) void vtr_kernel(const unsigned short* __restrict__ vp,
                                                  unsigned short* __restrict__ vt) {
  __shared__ unsigned short tile[64][72];
  const int jt = blockIdx.x, hh = blockIdx.y, bb = blockIdx.z;
  const int t = threadIdx.x, r = t >> 2, c0 = (t & 3) * 16;
  const unsigned short* src = vp + (size_t)(bb * SEQ + jt * 64 + r) * DMODEL + hh * DH + c0;
  *reinterpret_cast<short8v*>(&tile[r][c0]) = *reinterpret_cast<const short8v*>(src);
  *reinterpret_cast<short8v*>(&tile[r][c0 + 8]) = *reinterpret_cast<const short8v*>(src + 8);
  __syncthreads();
  short8v o0, o1;
#pragma unroll
  for (int e = 0; e < 8; ++e) o0[e] = (short)tile[c0 + e][r];
#pragma unroll
  for (int e = 0; e < 8; ++e) o1[e] = (short)tile[c0 + 8 + e][r];
  unsigned short* dst = vt + (size_t)((bb * 8 + hh) * 64 + r) * SEQ + jt * 64 + c0;
  *reinterpret_cast<short8v*>(dst) = o0;
  *reinterpret_cast<short8v*>(dst + 8) = o1;
}

// ---------------------------------------------------------------------------
// MFMA GEMM body: C[M,512] = (A[M,512] @ Wt^T + bias) * scale
// AF32: A is f32 (convert to bf16 during staging) or bf16.
// 128x64 tile, 256 thr (4 waves 2x2), BK=64, padded LDS.
// ---------------------------------------------------------------------------
template <int AF32, int OUTF32>
__device__ __forceinline__ void gemm_body(
    const void* __restrict__ Ap, const unsigned short* __restrict__ Wt,
    const float* __restrict__ bias, float scale, void* __restrict__ Cout) {
  __shared__ unsigned short Asl[128][72];
  __shared__ unsigned short Bsl[64][72];
  const int t = threadIdx.x;
  const int w = t >> 6, lane = t & 63, li = lane & 15, lg = lane >> 4;
  const int wr = w >> 1, wc = w & 1;
  const int rowBase = blockIdx.y * 128, colBase = blockIdx.x * 64;

  f32x4 zero4 = {0.f, 0.f, 0.f, 0.f};
  f32x4 acc[4][2];
#pragma unroll
  for (int mi = 0; mi < 4; ++mi)
#pragma unroll
    for (int nj = 0; nj < 2; ++nj) acc[mi][nj] = zero4;

  const int r = t >> 1, hf = (t & 1) * 32;       // A staging: row, 32-elem half
  const int br = t >> 2, bq = (t & 3) * 16;      // B staging: row, 16-elem quarter

  for (int k0 = 0; k0 < 512; k0 += 64) {
    if (AF32) {
      const float* src = reinterpret_cast<const float*>(Ap) +
                         (size_t)(rowBase + r) * 512 + k0 + hf;
#pragma unroll
      for (int qq = 0; qq < 4; ++qq) {
        float4 f0 = *reinterpret_cast<const float4*>(src + qq * 8);
        float4 f1 = *reinterpret_cast<const float4*>(src + qq * 8 + 4);
        short8v o;
        o[0] = (short)f2bf(f0.x); o[1] = (short)f2bf(f0.y);
        o[2] = (short)f2bf(f0.z); o[3] = (short)f2bf(f0.w);
        o[4] = (short)f2bf(f1.x); o[5] = (short)f2bf(f1.y);
        o[6] = (short)f2bf(f1.z); o[7] = (short)f2bf(f1.w);
        *reinterpret_cast<short8v*>(&Asl[r][hf + qq * 8]) = o;
      }
    } else {
      const unsigned short* src = reinterpret_cast<const unsigned short*>(Ap) +
                                  (size_t)(rowBase + r) * 512 + k0 + hf;
#pragma unroll
      for (int qq = 0; qq < 4; ++qq)
        *reinterpret_cast<short8v*>(&Asl[r][hf + qq * 8]) =
            *reinterpret_cast<const short8v*>(src + qq * 8);
    }
    {
      const unsigned short* src = Wt + (size_t)(colBase + br) * 512 + k0 + bq;
      *reinterpret_cast<short8v*>(&Bsl[br][bq]) = *reinterpret_cast<const short8v*>(src);
      *reinterpret_cast<short8v*>(&Bsl[br][bq + 8]) = *reinterpret_cast<const short8v*>(src + 8);
    }
    __syncthreads();
#pragma unroll
    for (int kk = 0; kk < 2; ++kk) {
      short8v af[4], bf[2];
#pragma unroll
      for (int mi = 0; mi < 4; ++mi)
        af[mi] = *reinterpret_cast<short8v*>(&Asl[wr * 64 + mi * 16 + li][kk * 32 + lg * 8]);
#pragma unroll
      for (int nj = 0; nj < 2; ++nj)
        bf[nj] = *reinterpret_cast<short8v*>(&Bsl[wc * 32 + nj * 16 + li][kk * 32 + lg * 8]);
#pragma unroll
      for (int mi = 0; mi < 4; ++mi)
#pragma unroll
        for (int nj = 0; nj < 2; ++nj) acc[mi][nj] = MFMA16(af[mi], bf[nj], acc[mi][nj]);
    }
    __syncthreads();
  }
#pragma unroll
  for (int nj = 0; nj < 2; ++nj) {
    const int col = colBase + wc * 32 + nj * 16 + li;
    const float bv = bias[col];
#pragma unroll
    for (int mi = 0; mi < 4; ++mi) {
#pragma unroll
      for (int rr = 0; rr < 4; ++rr) {
        const int row = rowBase + wr * 64 + mi * 16 + lg * 4 + rr;
        const float v = (acc[mi][nj][rr] + bv) * scale;
        if (OUTF32)
          reinterpret_cast<float*>(Cout)[(size_t)row * 512 + col] = v;
        else
          reinterpret_cast<unsigned short*>(Cout)[(size_t)row * 512 + col] = f2bf(v);
      }
    }
  }
}

// q- and k-projections fused in one dispatch (blockIdx.z selects)
__global__ __launch_bounds__(256) void gemm_qk(
    const float* __restrict__ q, const float* __restrict__ k,
    const unsigned short* __restrict__ Wqt, const unsigned short* __restrict__ Wkt,
    const float* __restrict__ bq, const float* __restrict__ bk,
    unsigned short* __restrict__ qpb, unsigned short* __restrict__ kpb) {
  const int z = blockIdx.z;
  const void* A = z ? (const void*)k : (const void*)q;
  const unsigned short* Wt = z ? Wkt : Wqt;
  const float* bias = z ? bk : bq;
  const float scale = z ? 1.0f : 0.125f;
  void* C = z ? (void*)kpb : (void*)qpb;
  gemm_body<1, 0>(A, Wt, bias, scale, C);
}

__global__ __launch_bounds__(256) void gemm_vp(
    const unsigned short* __restrict__ kpb, const unsigned short* __restrict__ Wvt,
    const float* __restrict__ bv, unsigned short* __restrict__ vpb) {
  gemm_body<0, 0>(kpb, Wvt, bv, 1.0f, vpb);
}

__global__ __launch_bounds__(256) void gemm_out(
    const unsigned short* __restrict__ attnb, const unsigned short* __restrict__ Wot,
    const float* __restrict__ bo, float* __restrict__ out) {
  gemm_body<0, 1>(attnb, Wot, bo, 1.0f, out);
}

// ---------------------------------------------------------------------------
// Traffic-shared MFMA flash attention (unchanged from R7's 59 us version).
// ---------------------------------------------------------------------------
__global__ __launch_bounds__(512, 4) void attn_mfma(
    const unsigned short* __restrict__ qp, const unsigned short* __restrict__ kp,
    const unsigned short* __restrict__ vt, const float* __restrict__ pos,
    const int* __restrict__ qmask, const int* __restrict__ kmask,
    unsigned short* __restrict__ outb) {
  const int bx = blockIdx.x;
  const int qc = bx >> 6, h = (bx >> 3) & 7, b = bx & 7;
  const int t = threadIdx.x, w = t >> 6, lane = t & 63, li = lane & 15, lg = lane >> 4;
  const int qrow = qc * 128 + w * 16;

  __shared__ unsigned short Kl[2][64 * 72];
  __shared__ unsigned short Vl[2][64 * 72];
  __shared__ unsigned short Pl[8][16 * 72];

  const size_t qg = (size_t)(b * SEQ + qrow + li) * DMODEL + h * DH;
  const short8v qf0 = *reinterpret_cast<const short8v*>(qp + qg + lg * 8);
  const short8v qf1 = *reinterpret_cast<const short8v*>(qp + qg + 32 + lg * 8);
  const int qmv = qmask[b * SEQ + qrow + li];

  f32x4 zero4 = {0.f, 0.f, 0.f, 0.f};
  f32x4 acc_o[4];
#pragma unroll
  for (int n = 0; n < 4; ++n) acc_o[n] = zero4;
  float m = -3e38f, l = 0.f;

  const int srow = t >> 3, schk = (t & 7) * 8;
  const unsigned short* kgp = kp + (size_t)(b * SEQ + srow) * DMODEL + h * DH + schk;
  const unsigned short* vgp = vt + ((size_t)((b * 8 + h) * 64) + srow) * SEQ + schk;
  const int sldst = srow * 72 + schk;

  const float* posb = pos + (size_t)(b * SEQ + qrow + li) * SEQ;
  const int* kmb = kmask + b * SEQ;

  {
    short8v kr = *reinterpret_cast<const short8v*>(kgp);
    short8v vr = *reinterpret_cast<const short8v*>(vgp);
    *reinterpret_cast<short8v*>(&Kl[0][sldst]) = kr;
    *reinterpret_cast<short8v*>(&Vl[0][sldst]) = vr;
  }
  __syncthreads();

  int buf = 0;
  for (int kt = 0; kt < 16; ++kt) {
    const int kbase = kt * 64;

    short8v kr, vr;
    if (kt < 15) {
      kr = *reinterpret_cast<const short8v*>(kgp + (size_t)(kbase + 64) * DMODEL);
      vr = *reinterpret_cast<const short8v*>(vgp + kbase + 64);
    }

    f32x4 pvn[4];
    i32x4 kmn[4];
#pragma unroll
    for (int n = 0; n < 4; ++n) {
      pvn[n] = *reinterpret_cast<const f32x4*>(posb + kbase + n * 16 + lg * 4);
      kmn[n] = *reinterpret_cast<const i32x4*>(kmb + kbase + n * 16 + lg * 4);
    }

    f32x4 x4[4];
    __builtin_amdgcn_s_setprio(1);
#pragma unroll
    for (int n = 0; n < 4; ++n) {
      short8v kfa = *reinterpret_cast<short8v*>(&Kl[buf][(n * 16 + li) * 72 + lg * 8]);
      short8v kfb = *reinterpret_cast<short8v*>(&Kl[buf][(n * 16 + li) * 72 + 32 + lg * 8]);
      x4[n] = MFMA16(kfa, qf0, zero4);
      x4[n] = MFMA16(kfb, qf1, x4[n]);
    }
    __builtin_amdgcn_s_setprio(0);

    float x[4][4];
    float tm = -3e38f;
#pragma unroll
    for (int n = 0; n < 4; ++n)
#pragma unroll
      for (int r = 0; r < 4; ++r) {
        float xx = x4[n][r] + pvn[n][r];
        if ((qmv != 0) != (kmn[n][r] != 0)) xx = -1e30f;
        x[n][r] = xx;
        tm = fmaxf(tm, xx);
      }
    tm = fmaxf(tm, __shfl_xor(tm, 16));
    tm = fmaxf(tm, __shfl_xor(tm, 32));
    const float mn = fmaxf(m, tm);
    const float rs = __expf(m - mn);
    m = mn;
    float psum = 0.f;
#pragma unroll
    for (int n = 0; n < 4; ++n)
#pragma unroll
      for (int r = 0; r < 4; ++r) {
        const float p = __expf(x[n][r] - m);
        x[n][r] = p;
        psum += p;
      }
    psum += __shfl_xor(psum, 16);
    psum += __shfl_xor(psum, 32);
    l = l * rs + psum;
    float rsb[4];
#pragma unroll
    for (int r = 0; r < 4; ++r) rsb[r] = __shfl(rs, lg * 4 + r, 16);
#pragma unroll
    for (int n = 0; n < 4; ++n)
#pragma unroll
      for (int r = 0; r < 4; ++r) acc_o[n][r] *= rsb[r];

#pragma unroll
    for (int n = 0; n < 4; ++n) {
      unsigned int lo = (unsigned int)f2bf(x[n][0]) | ((unsigned int)f2bf(x[n][1]) << 16);
      unsigned int hi = (unsigned int)f2bf(x[n][2]) | ((unsigned int)f2bf(x[n][3]) << 16);
      *reinterpret_cast<uint2*>(&Pl[w][li * 72 + n * 16 + lg * 4]) = make_uint2(lo, hi);
    }
    asm volatile("s_waitcnt lgkmcnt(0)" ::: "memory");
    __builtin_amdgcn_sched_barrier(0);
    const short8v pf0 = *reinterpret_cast<short8v*>(&Pl[w][li * 72 + lg * 8]);
    const short8v pf1 = *reinterpret_cast<short8v*>(&Pl[w][li * 72 + 32 + lg * 8]);

    __builtin_amdgcn_s_setprio(1);
#pragma unroll
    for (int n = 0; n < 4; ++n) {
      short8v vfa = *reinterpret_cast<short8v*>(&Vl[buf][(n * 16 + li) * 72 + lg * 8]);
      short8v vfb = *reinterpret_cast<short8v*>(&Vl[buf][(n * 16 + li) * 72 + 32 + lg * 8]);
      acc_o[n] = MFMA16(pf0, vfa, acc_o[n]);
      acc_o[n] = MFMA16(pf1, vfb, acc_o[n]);
    }
    __builtin_amdgcn_s_setprio(0);

    if (kt < 15) {
      *reinterpret_cast<short8v*>(&Kl[buf ^ 1][sldst]) = kr;
      *reinterpret_cast<short8v*>(&Vl[buf ^ 1][sldst]) = vr;
      __syncthreads();
      buf ^= 1;
    }
  }

  const float linv = 1.f / l;
  float lb[4];
#pragma unroll
  for (int r = 0; r < 4; ++r) lb[r] = __shfl(linv, lg * 4 + r, 16);
  unsigned short* ob = outb + (size_t)(b * SEQ + qrow) * DMODEL + h * DH;
#pragma unroll
  for (int n = 0; n < 4; ++n)
#pragma unroll
    for (int r = 0; r < 4; ++r)
      ob[(size_t)(lg * 4 + r) * DMODEL + n * 16 + li] = f2bf(acc_o[n][r] * lb[r]);
}

// ---------------------------------------------------------------------------
extern "C" void kernel_launch(void* const* d_in, const int* in_sizes, int n_in,
                              void* d_out, int out_size, void* d_ws, size_t ws_size,
                              hipStream_t stream) {
  const float* q   = (const float*)d_in[0];
  const float* k   = (const float*)d_in[1];
  const int*   qm  = (const int*)d_in[2];
  const int*   km  = (const int*)d_in[3];
  const float* pos = (const float*)d_in[4];
  const float* Wq  = (const float*)d_in[5];
  const float* bq  = (const float*)d_in[6];
  const float* Wk  = (const float*)d_in[7];
  const float* bk  = (const float*)d_in[8];
  const float* Wv  = (const float*)d_in[9];
  const float* bv  = (const float*)d_in[10];
  const float* Wo  = (const float*)d_in[11];
  const float* bo  = (const float*)d_in[12];
  float* out = (float*)d_out;

  char* ws = (char*)d_ws;
  const size_t MB8 = (size_t)TOK * DMODEL * 2;  // 8 MB per bf16 [8192][512]
  unsigned short* qpb   = (unsigned short*)(ws);
  unsigned short* kpb   = (unsigned short*)(ws + 1 * MB8);
  unsigned short* vpb   = (unsigned short*)(ws + 2 * MB8);
  unsigned short* attnb = (unsigned short*)(ws + 3 * MB8);
  unsigned short* vtb   = (unsigned short*)(ws + 4 * MB8);
  unsigned short* Wqt   = (unsigned short*)(ws + 5 * MB8);
  unsigned short* Wkt   = Wqt + (size_t)512 * 512;
  unsigned short* Wvt   = Wkt + (size_t)512 * 512;
  unsigned short* Wot   = Wvt + (size_t)512 * 512;

  hipLaunchKernelGGL(wtr4_kernel, dim3(8, 8, 4), dim3(256), 0, stream,
                     Wq, Wk, Wv, Wo, Wqt, Wkt, Wvt, Wot);

  const dim3 ggrid(DMODEL / 64, TOK / 128);  // (8, 64)
  hipLaunchKernelGGL(gemm_qk, dim3(8, 64, 2), dim3(256), 0, stream,
                     q, k, Wqt, Wkt, bq, bk, qpb, kpb);
  hipLaunchKernelGGL(gemm_vp, ggrid, dim3(256), 0, stream, kpb, Wvt, bv, vpb);

  hipLaunchKernelGGL(vtr_kernel, dim3(16, 8, 8), dim3(256), 0, stream, vpb, vtb);

  hipLaunchKernelGGL(attn_mfma, dim3(512), dim3(512), 0, stream,
                     qpb, kpb, vtb, pos, qm, km, attnb);

  hipLaunchKernelGGL(gemm_out, ggrid, dim3(256), 0, stream, attnb, Wot, bo, out);
}

// Round 9
// 126.330 us; speedup vs baseline: 6.8413x; 1.1427x over previous
//
#include <hip/hip_runtime.h>
#include <hip/hip_bf16.h>
#include <math.h>

// Problem constants: B=8, H=W=32, D=512, NH=8, DKH=DVH=64
#define TOK 8192
#define DMODEL 512
#define SEQ 1024
#define NHEADS 8
#define DH 64
#define NBATCH 8

typedef __attribute__((ext_vector_type(8))) short short8v;   // 8 bf16 = 4 VGPR
typedef __attribute__((ext_vector_type(4))) float f32x4;
typedef __attribute__((ext_vector_type(4))) int i32x4;

#define MFMA16(a, b, c) __builtin_amdgcn_mfma_f32_16x16x32_bf16(a, b, c, 0, 0, 0)

// HW RNE f32->bf16 (single v_cvt; pairs fuse to v_cvt_pk_bf16_f32)
__device__ __forceinline__ unsigned short f2bf(float x) {
  __hip_bfloat16 h = __float2bfloat16(x);
  unsigned short u;
  __builtin_memcpy(&u, &h, 2);
  return u;
}
__device__ __forceinline__ unsigned int pk2(float a, float b) {
  return (unsigned int)f2bf(a) | ((unsigned int)f2bf(b) << 16);
}

// ---------------------------------------------------------------------------
// Weight transpose + convert: Wt[n][k] = bf16(W[k][n]), 512x512. 4 matrices
// in one dispatch (blockIdx.z selects).
// ---------------------------------------------------------------------------
__global__ __launch_bounds__(256) void wtr4_kernel(
    const float* __restrict__ W0, const float* __restrict__ W1,
    const float* __restrict__ W2, const float* __restrict__ W3,
    unsigned short* __restrict__ T0, unsigned short* __restrict__ T1,
    unsigned short* __restrict__ T2, unsigned short* __restrict__ T3) {
  __shared__ unsigned short tile[64][72];
  const int z = blockIdx.z;
  const float* W = (z == 0) ? W0 : (z == 1) ? W1 : (z == 2) ? W2 : W3;
  unsigned short* Wt = (z == 0) ? T0 : (z == 1) ? T1 : (z == 2) ? T2 : T3;
  const int kt = blockIdx.x, nt = blockIdx.y;
  const int t = threadIdx.x, r = t >> 2, c0 = (t & 3) * 16;
  const float* src = W + (size_t)(kt * 64 + r) * 512 + nt * 64 + c0;
  short8v v0, v1;
#pragma unroll
  for (int e = 0; e < 4; ++e) {
    float4 f = *reinterpret_cast<const float4*>(src + e * 4);
    short* dstv = (e < 2) ? (short*)&v0 : (short*)&v1;
    dstv[(e & 1) * 4 + 0] = (short)f2bf(f.x);
    dstv[(e & 1) * 4 + 1] = (short)f2bf(f.y);
    dstv[(e & 1) * 4 + 2] = (short)f2bf(f.z);
    dstv[(e & 1) * 4 + 3] = (short)f2bf(f.w);
  }
  *reinterpret_cast<short8v*>(&tile[r][c0]) = v0;
  *reinterpret_cast<short8v*>(&tile[r][c0 + 8]) = v1;
  __syncthreads();
  short8v o0, o1;
#pragma unroll
  for (int e = 0; e < 8; ++e) o0[e] = (short)tile[c0 + e][r];
#pragma unroll
  for (int e = 0; e < 8; ++e) o1[e] = (short)tile[c0 + 8 + e][r];
  unsigned short* dst = Wt + (size_t)(nt * 64 + r) * 512 + kt * 64 + c0;
  *reinterpret_cast<short8v*>(dst) = o0;
  *reinterpret_cast<short8v*>(dst + 8) = o1;
}

// ---------------------------------------------------------------------------
// MFMA GEMM body: C[M,512] = (A[M,512] @ Wt^T + bias) * scale
// 128x128 tile, 256 thr (4 waves 2x2, 64x64 each), BK=64, padded LDS.
// AF32: A is f32 (convert during staging). OUTMODE: 0=bf16 row-major,
// 1=f32 row-major, 2=bf16 transposed into vt[(b*8+h)*64+d][token].
// ---------------------------------------------------------------------------
template <int AF32, int OUTMODE>
__device__ __forceinline__ void gemm_body(
    const void* __restrict__ Ap, const unsigned short* __restrict__ Wt,
    const float* __restrict__ bias, float scale, void* __restrict__ Cout) {
  __shared__ unsigned short Asl[128][72];
  __shared__ unsigned short Bsl[128][72];
  const int t = threadIdx.x;
  const int w = t >> 6, lane = t & 63, li = lane & 15, lg = lane >> 4;
  const int wr = w >> 1, wc = w & 1;
  const int rowBase = blockIdx.y * 128, colBase = blockIdx.x * 128;

  f32x4 zero4 = {0.f, 0.f, 0.f, 0.f};
  f32x4 acc[4][4];
#pragma unroll
  for (int mi = 0; mi < 4; ++mi)
#pragma unroll
    for (int nj = 0; nj < 4; ++nj) acc[mi][nj] = zero4;

  const int sr = t >> 1, sh = (t & 1) * 32;  // staging: row, 32-elem half

  for (int k0 = 0; k0 < 512; k0 += 64) {
    if (AF32) {
      const float* src = reinterpret_cast<const float*>(Ap) +
                         (size_t)(rowBase + sr) * 512 + k0 + sh;
#pragma unroll
      for (int qq = 0; qq < 4; ++qq) {
        float4 f0 = *reinterpret_cast<const float4*>(src + qq * 8);
        float4 f1 = *reinterpret_cast<const float4*>(src + qq * 8 + 4);
        short8v o;
        o[0] = (short)f2bf(f0.x); o[1] = (short)f2bf(f0.y);
        o[2] = (short)f2bf(f0.z); o[3] = (short)f2bf(f0.w);
        o[4] = (short)f2bf(f1.x); o[5] = (short)f2bf(f1.y);
        o[6] = (short)f2bf(f1.z); o[7] = (short)f2bf(f1.w);
        *reinterpret_cast<short8v*>(&Asl[sr][sh + qq * 8]) = o;
      }
    } else {
      const unsigned short* src = reinterpret_cast<const unsigned short*>(Ap) +
                                  (size_t)(rowBase + sr) * 512 + k0 + sh;
#pragma unroll
      for (int qq = 0; qq < 4; ++qq)
        *reinterpret_cast<short8v*>(&Asl[sr][sh + qq * 8]) =
            *reinterpret_cast<const short8v*>(src + qq * 8);
    }
    {
      const unsigned short* src = Wt + (size_t)(colBase + sr) * 512 + k0 + sh;
#pragma unroll
      for (int qq = 0; qq < 4; ++qq)
        *reinterpret_cast<short8v*>(&Bsl[sr][sh + qq * 8]) =
            *reinterpret_cast<const short8v*>(src + qq * 8);
    }
    __syncthreads();
#pragma unroll
    for (int kk = 0; kk < 2; ++kk) {
      short8v af[4], bf[4];
#pragma unroll
      for (int mi = 0; mi < 4; ++mi)
        af[mi] = *reinterpret_cast<short8v*>(&Asl[wr * 64 + mi * 16 + li][kk * 32 + lg * 8]);
#pragma unroll
      for (int nj = 0; nj < 4; ++nj)
        bf[nj] = *reinterpret_cast<short8v*>(&Bsl[wc * 64 + nj * 16 + li][kk * 32 + lg * 8]);
#pragma unroll
      for (int mi = 0; mi < 4; ++mi)
#pragma unroll
        for (int nj = 0; nj < 4; ++nj) acc[mi][nj] = MFMA16(af[mi], bf[nj], acc[mi][nj]);
    }
    __syncthreads();
  }

#pragma unroll
  for (int nj = 0; nj < 4; ++nj) {
    const int col = colBase + wc * 64 + nj * 16 + li;
    const float bv = bias[col];
#pragma unroll
    for (int mi = 0; mi < 4; ++mi) {
      const int row0 = rowBase + wr * 64 + mi * 16 + lg * 4;
      if (OUTMODE == 2) {
        // vt[(b*8+h)*64 + d][token]; 4 consecutive tokens per lane -> uint2
        const int hh = col >> 6, dd = col & 63;
        const int bb = row0 >> 10, jj = row0 & 1023;
        unsigned short* dst =
            reinterpret_cast<unsigned short*>(Cout) +
            ((size_t)((bb * 8 + hh) * 64 + dd)) * SEQ + jj;
        float v0 = (acc[mi][nj][0] + bv) * scale;
        float v1 = (acc[mi][nj][1] + bv) * scale;
        float v2 = (acc[mi][nj][2] + bv) * scale;
        float v3 = (acc[mi][nj][3] + bv) * scale;
        *reinterpret_cast<uint2*>(dst) = make_uint2(pk2(v0, v1), pk2(v2, v3));
      } else {
#pragma unroll
        for (int rr = 0; rr < 4; ++rr) {
          const int row = row0 + rr;
          const float v = (acc[mi][nj][rr] + bv) * scale;
          if (OUTMODE == 1)
            reinterpret_cast<float*>(Cout)[(size_t)row * 512 + col] = v;
          else
            reinterpret_cast<unsigned short*>(Cout)[(size_t)row * 512 + col] = f2bf(v);
        }
      }
    }
  }
}

// q- and k-projections fused in one dispatch (blockIdx.z selects)
__global__ __launch_bounds__(256) void gemm_qk(
    const float* __restrict__ q, const float* __restrict__ k,
    const unsigned short* __restrict__ Wqt, const unsigned short* __restrict__ Wkt,
    const float* __restrict__ bq, const float* __restrict__ bk,
    unsigned short* __restrict__ qpb, unsigned short* __restrict__ kpb) {
  const int z = blockIdx.z;
  const void* A = z ? (const void*)k : (const void*)q;
  const unsigned short* Wt = z ? Wkt : Wqt;
  const float* bias = z ? bk : bq;
  const float scale = z ? 1.0f : 0.125f;
  void* C = z ? (void*)kpb : (void*)qpb;
  gemm_body<1, 0>(A, Wt, bias, scale, C);
}

// v-projection writing transposed vt directly (kills the vtr pass)
__global__ __launch_bounds__(256) void gemm_vp(
    const unsigned short* __restrict__ kpb, const unsigned short* __restrict__ Wvt,
    const float* __restrict__ bv, unsigned short* __restrict__ vtb) {
  gemm_body<0, 2>(kpb, Wvt, bv, 1.0f, vtb);
}

__global__ __launch_bounds__(256) void gemm_out(
    const unsigned short* __restrict__ attnb, const unsigned short* __restrict__ Wot,
    const float* __restrict__ bo, float* __restrict__ out) {
  gemm_body<0, 1>(attnb, Wot, bo, 1.0f, out);
}

// ---------------------------------------------------------------------------
// Traffic-shared MFMA flash attention (R7 structure; HW bf16 casts).
// ---------------------------------------------------------------------------
__global__ __launch_bounds__(512, 4) void attn_mfma(
    const unsigned short* __restrict__ qp, const unsigned short* __restrict__ kp,
    const unsigned short* __restrict__ vt, const float* __restrict__ pos,
    const int* __restrict__ qmask, const int* __restrict__ kmask,
    unsigned short* __restrict__ outb) {
  const int bx = blockIdx.x;
  const int qc = bx >> 6, h = (bx >> 3) & 7, b = bx & 7;
  const int t = threadIdx.x, w = t >> 6, lane = t & 63, li = lane & 15, lg = lane >> 4;
  const int qrow = qc * 128 + w * 16;

  __shared__ unsigned short Kl[2][64 * 72];
  __shared__ unsigned short Vl[2][64 * 72];
  __shared__ unsigned short Pl[8][16 * 72];

  const size_t qg = (size_t)(b * SEQ + qrow + li) * DMODEL + h * DH;
  const short8v qf0 = *reinterpret_cast<const short8v*>(qp + qg + lg * 8);
  const short8v qf1 = *reinterpret_cast<const short8v*>(qp + qg + 32 + lg * 8);
  const int qmv = qmask[b * SEQ + qrow + li];

  f32x4 zero4 = {0.f, 0.f, 0.f, 0.f};
  f32x4 acc_o[4];
#pragma unroll
  for (int n = 0; n < 4; ++n) acc_o[n] = zero4;
  float m = -3e38f, l = 0.f;

  const int srow = t >> 3, schk = (t & 7) * 8;
  const unsigned short* kgp = kp + (size_t)(b * SEQ + srow) * DMODEL + h * DH + schk;
  const unsigned short* vgp = vt + ((size_t)((b * 8 + h) * 64) + srow) * SEQ + schk;
  const int sldst = srow * 72 + schk;

  const float* posb = pos + (size_t)(b * SEQ + qrow + li) * SEQ;
  const int* kmb = kmask + b * SEQ;

  {
    short8v kr = *reinterpret_cast<const short8v*>(kgp);
    short8v vr = *reinterpret_cast<const short8v*>(vgp);
    *reinterpret_cast<short8v*>(&Kl[0][sldst]) = kr;
    *reinterpret_cast<short8v*>(&Vl[0][sldst]) = vr;
  }
  __syncthreads();

  int buf = 0;
  for (int kt = 0; kt < 16; ++kt) {
    const int kbase = kt * 64;

    short8v kr, vr;
    if (kt < 15) {
      kr = *reinterpret_cast<const short8v*>(kgp + (size_t)(kbase + 64) * DMODEL);
      vr = *reinterpret_cast<const short8v*>(vgp + kbase + 64);
    }

    f32x4 pvn[4];
    i32x4 kmn[4];
#pragma unroll
    for (int n = 0; n < 4; ++n) {
      pvn[n] = *reinterpret_cast<const f32x4*>(posb + kbase + n * 16 + lg * 4);
      kmn[n] = *reinterpret_cast<const i32x4*>(kmb + kbase + n * 16 + lg * 4);
    }

    f32x4 x4[4];
    __builtin_amdgcn_s_setprio(1);
#pragma unroll
    for (int n = 0; n < 4; ++n) {
      short8v kfa = *reinterpret_cast<short8v*>(&Kl[buf][(n * 16 + li) * 72 + lg * 8]);
      short8v kfb = *reinterpret_cast<short8v*>(&Kl[buf][(n * 16 + li) * 72 + 32 + lg * 8]);
      x4[n] = MFMA16(kfa, qf0, zero4);
      x4[n] = MFMA16(kfb, qf1, x4[n]);
    }
    __builtin_amdgcn_s_setprio(0);

    float x[4][4];
    float tm = -3e38f;
#pragma unroll
    for (int n = 0; n < 4; ++n)
#pragma unroll
      for (int r = 0; r < 4; ++r) {
        float xx = x4[n][r] + pvn[n][r];
        if ((qmv != 0) != (kmn[n][r] != 0)) xx = -1e30f;
        x[n][r] = xx;
        tm = fmaxf(tm, xx);
      }
    tm = fmaxf(tm, __shfl_xor(tm, 16));
    tm = fmaxf(tm, __shfl_xor(tm, 32));
    const float mn = fmaxf(m, tm);
    const float rs = __expf(m - mn);
    m = mn;
    float psum = 0.f;
#pragma unroll
    for (int n = 0; n < 4; ++n)
#pragma unroll
      for (int r = 0; r < 4; ++r) {
        const float p = __expf(x[n][r] - m);
        x[n][r] = p;
        psum += p;
      }
    psum += __shfl_xor(psum, 16);
    psum += __shfl_xor(psum, 32);
    l = l * rs + psum;
    float rsb[4];
#pragma unroll
    for (int r = 0; r < 4; ++r) rsb[r] = __shfl(rs, lg * 4 + r, 16);
#pragma unroll
    for (int n = 0; n < 4; ++n)
#pragma unroll
      for (int r = 0; r < 4; ++r) acc_o[n][r] *= rsb[r];

#pragma unroll
    for (int n = 0; n < 4; ++n) {
      *reinterpret_cast<uint2*>(&Pl[w][li * 72 + n * 16 + lg * 4]) =
          make_uint2(pk2(x[n][0], x[n][1]), pk2(x[n][2], x[n][3]));
    }
    asm volatile("s_waitcnt lgkmcnt(0)" ::: "memory");
    __builtin_amdgcn_sched_barrier(0);
    const short8v pf0 = *reinterpret_cast<short8v*>(&Pl[w][li * 72 + lg * 8]);
    const short8v pf1 = *reinterpret_cast<short8v*>(&Pl[w][li * 72 + 32 + lg * 8]);

    __builtin_amdgcn_s_setprio(1);
#pragma unroll
    for (int n = 0; n < 4; ++n) {
      short8v vfa = *reinterpret_cast<short8v*>(&Vl[buf][(n * 16 + li) * 72 + lg * 8]);
      short8v vfb = *reinterpret_cast<short8v*>(&Vl[buf][(n * 16 + li) * 72 + 32 + lg * 8]);
      acc_o[n] = MFMA16(pf0, vfa, acc_o[n]);
      acc_o[n] = MFMA16(pf1, vfb, acc_o[n]);
    }
    __builtin_amdgcn_s_setprio(0);

    if (kt < 15) {
      *reinterpret_cast<short8v*>(&Kl[buf ^ 1][sldst]) = kr;
      *reinterpret_cast<short8v*>(&Vl[buf ^ 1][sldst]) = vr;
      __syncthreads();
      buf ^= 1;
    }
  }

  const float linv = 1.f / l;
  float lb[4];
#pragma unroll
  for (int r = 0; r < 4; ++r) lb[r] = __shfl(linv, lg * 4 + r, 16);
  unsigned short* ob = outb + (size_t)(b * SEQ + qrow) * DMODEL + h * DH;
#pragma unroll
  for (int n = 0; n < 4; ++n)
#pragma unroll
    for (int r = 0; r < 4; ++r)
      ob[(size_t)(lg * 4 + r) * DMODEL + n * 16 + li] = f2bf(acc_o[n][r] * lb[r]);
}

// ---------------------------------------------------------------------------
extern "C" void kernel_launch(void* const* d_in, const int* in_sizes, int n_in,
                              void* d_out, int out_size, void* d_ws, size_t ws_size,
                              hipStream_t stream) {
  const float* q   = (const float*)d_in[0];
  const float* k   = (const float*)d_in[1];
  const int*   qm  = (const int*)d_in[2];
  const int*   km  = (const int*)d_in[3];
  const float* pos = (const float*)d_in[4];
  const float* Wq  = (const float*)d_in[5];
  const float* bq  = (const float*)d_in[6];
  const float* Wk  = (const float*)d_in[7];
  const float* bk  = (const float*)d_in[8];
  const float* Wv  = (const float*)d_in[9];
  const float* bv  = (const float*)d_in[10];
  const float* Wo  = (const float*)d_in[11];
  const float* bo  = (const float*)d_in[12];
  float* out = (float*)d_out;

  char* ws = (char*)d_ws;
  const size_t MB8 = (size_t)TOK * DMODEL * 2;  // 8 MB per bf16 [8192][512]
  unsigned short* qpb   = (unsigned short*)(ws);
  unsigned short* kpb   = (unsigned short*)(ws + 1 * MB8);
  unsigned short* attnb = (unsigned short*)(ws + 2 * MB8);
  unsigned short* vtb   = (unsigned short*)(ws + 3 * MB8);
  unsigned short* Wqt   = (unsigned short*)(ws + 4 * MB8);
  unsigned short* Wkt   = Wqt + (size_t)512 * 512;
  unsigned short* Wvt   = Wkt + (size_t)512 * 512;
  unsigned short* Wot   = Wvt + (size_t)512 * 512;

  hipLaunchKernelGGL(wtr4_kernel, dim3(8, 8, 4), dim3(256), 0, stream,
                     Wq, Wk, Wv, Wo, Wqt, Wkt, Wvt, Wot);

  const dim3 ggrid(DMODEL / 128, TOK / 128);  // (4, 64)
  hipLaunchKernelGGL(gemm_qk, dim3(4, 64, 2), dim3(256), 0, stream,
                     q, k, Wqt, Wkt, bq, bk, qpb, kpb);
  hipLaunchKernelGGL(gemm_vp, ggrid, dim3(256), 0, stream, kpb, Wvt, bv, vtb);

  hipLaunchKernelGGL(attn_mfma, dim3(512), dim3(512), 0, stream,
                     qpb, kpb, vtb, pos, qm, km, attnb);

  hipLaunchKernelGGL(gemm_out, ggrid, dim3(256), 0, stream, attnb, Wot, bo, out);
}